// Round 7
// baseline (1043.743 us; speedup 1.0000x reference)
//
#include <hip/hip_runtime.h>

#define NNODES 100000
#define NEDGES 1600000
#define NBKT 782          // buckets of 128 nodes: 782*128 = 100096 >= NNODES
#define PLANE_ELT ((size_t)NNODES * 16)

typedef __attribute__((ext_vector_type(8))) short bf16x8;
typedef __attribute__((ext_vector_type(4))) float f32x4;
typedef __attribute__((ext_vector_type(2))) float f32x2;

// ---------- bf16 helpers ----------
__device__ __forceinline__ float bf2f(unsigned v) {
  union { unsigned u; float f; } x; x.u = v << 16; return x.f;
}
__device__ __forceinline__ unsigned short f2bf(float f) {
  union { float f; unsigned u; } x; x.f = f;
  unsigned r = x.u + 0x7fffu + ((x.u >> 16) & 1u);
  return (unsigned short)(r >> 16);
}
__device__ __forceinline__ f32x2 unpk(unsigned u) {
  union { unsigned q; float f; } lo, hi;
  lo.q = u << 16; hi.q = u & 0xffff0000u;
  f32x2 r; r.x = lo.f; r.y = hi.f; return r;
}
__device__ __forceinline__ unsigned short ldcv(const void* p, int i, int f32) {
  return f32 ? f2bf(((const float*)p)[i]) : ((const unsigned short*)p)[i];
}
// per-wave i64 self-detection: high words of int64 node ids are all zero
__device__ __forceinline__ int detect_i64(const int* __restrict__ ei) {
  int lane = threadIdx.x & 63;
  int hv = ei[2 * lane + 1];
  unsigned long long nz = __ballot(hv != 0);
  return (__popcll(nz) < 4) ? 1 : 0;
}
__device__ __forceinline__ int edge_at(const int* __restrict__ ei, int j, int i64) {
  return i64 ? ei[2 * j] : ei[j];
}

__global__ void k_zero(int* __restrict__ p, int n) {
  int v = blockIdx.x * blockDim.x + threadIdx.x;
  if (v < n) p[v] = 0;
}

// ---------- bucketed CSR build (no global per-edge atomics) ----------
__global__ __launch_bounds__(256) void k_bcnt(const int* __restrict__ ei,
                                              int* __restrict__ bcnt,
                                              const unsigned* __restrict__ xw,
                                              int* __restrict__ flags) {
  __shared__ int h[NBKT];
  __shared__ int cF;
  int t = threadIdx.x;
  for (int i = t; i < NBKT; i += 256) h[i] = 0;
  if (blockIdx.x == 0 && t == 0) cF = 0;
  __syncthreads();
  if (blockIdx.x == 0) {
    int hf = 0;
    for (int i = t; i < 2048; i += 256) {
      unsigned lo = xw[i] & 0xffffu;
      unsigned e = (lo >> 7) & 0xffu;
      if (e >= 0xC0u) hf++;
    }
    atomicAdd(&cF, hf);
  }
  int i64 = detect_i64(ei);
  int e0 = blockIdx.x * 4096;
#pragma unroll
  for (int k = 0; k < 16; ++k) {
    int e = e0 + t + k * 256;
    if (e < NEDGES) {
      int d = edge_at(ei, NEDGES + e, i64);
      if ((unsigned)d < NNODES) atomicAdd(&h[d >> 7], 1);
    }
  }
  __syncthreads();
  for (int i = t; i < NBKT; i += 256)
    if (h[i]) atomicAdd(&bcnt[i], h[i]);
  if (blockIdx.x == 0 && t == 0) flags[0] = (cF > 32) ? 1 : 0;
}

__global__ void k_bscan2(const int* __restrict__ bcnt, int* __restrict__ bbase,
                         int* __restrict__ gcur) {
  int l = threadIdx.x;  // 64 lanes
  int v[13];
  int s = 0;
#pragma unroll
  for (int k = 0; k < 13; ++k) {
    int j = l * 13 + k;
    v[k] = (j < NBKT) ? bcnt[j] : 0;
    s += v[k];
  }
  int x = s;
#pragma unroll
  for (int o = 1; o < 64; o <<= 1) {
    int y = __shfl_up(x, o, 64);
    if (l >= o) x += y;
  }
  int excl = x - s;
#pragma unroll
  for (int k = 0; k < 13; ++k) {
    int j = l * 13 + k;
    if (j < NBKT) { bbase[j] = excl; gcur[j] = excl; }
    excl += v[k];
  }
  if (l == 63) bbase[NBKT] = x;
}

__global__ __launch_bounds__(256) void k_bstage(const int* __restrict__ ei,
                                                int* __restrict__ gcur,
                                                int* __restrict__ stage) {
  __shared__ int h[NBKT];
  __shared__ int base[NBKT];
  int t = threadIdx.x;
  for (int i = t; i < NBKT; i += 256) h[i] = 0;
  __syncthreads();
  int i64 = detect_i64(ei);
  int e0 = blockIdx.x * 4096;
  int bkt[16], lp[16], rec[16];
#pragma unroll
  for (int k = 0; k < 16; ++k) {
    bkt[k] = -1;
    int e = e0 + t + k * 256;
    if (e < NEDGES) {
      int d = edge_at(ei, NEDGES + e, i64);
      if ((unsigned)d < NNODES) {
        int s = edge_at(ei, e, i64);
        if ((unsigned)s >= NNODES) s = NNODES - 1;
        bkt[k] = d >> 7;
        rec[k] = ((d & 127) << 17) | s;
        lp[k] = atomicAdd(&h[bkt[k]], 1);
      }
    }
  }
  __syncthreads();
  for (int i = t; i < NBKT; i += 256)
    base[i] = h[i] ? atomicAdd(&gcur[i], h[i]) : 0;
  __syncthreads();
#pragma unroll
  for (int k = 0; k < 16; ++k)
    if (bkt[k] >= 0) stage[base[bkt[k]] + lp[k]] = rec[k];
}

__global__ __launch_bounds__(256) void k_bplace(const int* __restrict__ stage,
                                                const int* __restrict__ bbase,
                                                int* __restrict__ offs,
                                                float* __restrict__ dinv,
                                                int* __restrict__ csr_src) {
  __shared__ int h[128];
  __shared__ int cur[128];
  int b = blockIdx.x;
  int t = threadIdx.x;
  int n0 = b * 128;
  int NN = NNODES - n0; if (NN > 128) NN = 128;
  int s0 = bbase[b], s1 = bbase[b + 1];
  int cnt = s1 - s0;
  if (t < 128) h[t] = 0;
  __syncthreads();
  for (int i = t; i < cnt; i += 256) {
    int rec = stage[s0 + i];
    atomicAdd(&h[rec >> 17], 1);
  }
  __syncthreads();
  if (t < 64) {
    int a = h[2 * t], c = h[2 * t + 1];
    int s = a + c;
    int x = s;
#pragma unroll
    for (int o = 1; o < 64; o <<= 1) {
      int y = __shfl_up(x, o, 64);
      if (t >= o) x += y;
    }
    int excl = s0 + x - s;
    cur[2 * t] = excl;
    cur[2 * t + 1] = excl + a;
    if (2 * t < NN) {
      offs[n0 + 2 * t] = excl;
      dinv[n0 + 2 * t] = rsqrtf((float)a + 1.0f);
    }
    if (2 * t + 1 < NN) {
      offs[n0 + 2 * t + 1] = excl + a;
      dinv[n0 + 2 * t + 1] = rsqrtf((float)c + 1.0f);
    }
  }
  if (b == NBKT - 1 && t == 0) offs[NNODES] = s1;
  __syncthreads();
  for (int i = t; i < cnt; i += 256) {
    int rec = stage[s0 + i];
    int pos = atomicAdd(&cur[rec >> 17], 1);
    csr_src[pos] = rec & 0x1FFFF;
  }
}

// ---------- canonicalize + weight prep, one dispatch ----------
// y=0: x -> xb (row-major) and xs = x*dinv (16-col PLANES); y=1..6 biases; y=7 W-transposes.
struct CvtP {
  const void* src[7];
  unsigned short* dst[7];
  int n[7];
  const void* W[6];
  unsigned short* WT[6];
};

__global__ void k_cvt(CvtP p, const int* __restrict__ flags,
                      const float* __restrict__ dinv, unsigned short* __restrict__ xs) {
  int a = blockIdx.y;
  int f32 = flags[0];
  if (a < 7) {
    int n = p.n[a];
    const float* sf = (const float*)p.src[a];
    const unsigned short* sb = (const unsigned short*)p.src[a];
    unsigned short* d = p.dst[a];
    for (int i = blockIdx.x * blockDim.x + threadIdx.x; i < n; i += gridDim.x * blockDim.x) {
      if (a == 0) {
        float v = f32 ? sf[i] : bf2f((unsigned)sb[i]);
        d[i] = f32 ? f2bf(v) : sb[i];
        int row = i >> 7, col = i & 127;
        xs[(size_t)(col >> 4) * PLANE_ELT + (size_t)row * 16 + (col & 15)] =
            f2bf(v * dinv[row]);
      } else {
        d[i] = f32 ? f2bf(sf[i]) : sb[i];
      }
    }
  } else {
    int g = blockIdx.x * 256 + threadIdx.x;
    if (g < 32768) {
      int k = g >> 8, c = g & 255;
      p.WT[0][c * 128 + k] = ldcv(p.W[0], g, f32);
    } else if (g < 98304) {
      int l = g - 32768; int k = l >> 8, c = l & 255;
      p.WT[1][c * 256 + k] = ldcv(p.W[1], l, f32);
    } else if (g < 104448) {
      int l = g - 98304; int c = l >> 7, k = l & 127;
      p.WT[2][l] = (c < 40) ? ldcv(p.W[2], k * 40 + c, f32) : (unsigned short)0;
    } else if (g < 110592) {
      int l = g - 104448; int c = l >> 7, k = l & 127;
      p.WT[3][l] = (c < 40) ? ldcv(p.W[3], k * 40 + c, f32) : (unsigned short)0;
    } else if (g < 122880) {
      int l = g - 110592; int c = l >> 8, k = l & 255;
      p.WT[4][l] = (c < 40) ? ldcv(p.W[4], k * 40 + c, f32) : (unsigned short)0;
    } else if (g < 135168) {
      int l = g - 122880; int c = l >> 8, k = l & 255;
      p.WT[5][l] = (c < 40) ? ldcv(p.W[5], k * 40 + c, f32) : (unsigned short)0;
    }
  }
}

// ---------- plane-partitioned aggregation ----------
// IP/OP: [NP][N][16] bf16 planes, input prescaled by dinv[src].
// plane = (b&7) + 8*((b>>3)/2500) -> XCD-pinned via blockIdx%8; 3.2 MB/plane
// fits one XCD's 4 MB L2. Wave = 1 node: 8 edge-slots x 8 col-pairs,
// 8 edges per gather instr, 16 edges/iter with one-iter index prefetch,
// non-temporal csr loads. out[v] = dinv[v]*(sum + self).
template <int NPLANES>
__global__ __launch_bounds__(256) void k_aggp(
    const unsigned short* __restrict__ IP, unsigned short* __restrict__ OP,
    const int* __restrict__ offs, const int* __restrict__ csr_src,
    const float* __restrict__ dinv) {
  int b = blockIdx.x;
  int bb = b >> 3;
  int plane = (b & 7) + 8 * (bb / 2500);
  int j0 = bb % 2500;
  const int lane = threadIdx.x & 63;
  const int wvi = threadIdx.x >> 6;
  const int c = lane & 7;     // u32 col-pair (cols 2c, 2c+1)
  const int g = lane >> 3;    // edge slot [0,8)
  const unsigned short* ip = IP + (size_t)plane * PLANE_ELT;
  unsigned short* op = OP + (size_t)plane * PLANE_ELT;

  for (int j = j0; j < 25000; j += 2500) {
    int v = j * 4 + wvi;
    float dv = dinv[v];
    unsigned su = *(const unsigned*)(ip + (size_t)v * 16 + c * 2);
    f32x2 acc = unpk(su) * ((g == 0) ? 1.f : 0.f);
    int b0 = offs[v];
    int n = offs[v + 1] - b0;
    if (n > 0) {
      int e0 = g, e1 = 8 + g;
      int s0 = __builtin_nontemporal_load(csr_src + b0 + (e0 < n ? e0 : n - 1));
      int s1 = __builtin_nontemporal_load(csr_src + b0 + (e1 < n ? e1 : n - 1));
      float w0 = (e0 < n) ? 1.f : 0.f;
      float w1 = (e1 < n) ? 1.f : 0.f;
      for (int i = 0; i < n; i += 16) {
        unsigned u0 = *(const unsigned*)(ip + (size_t)s0 * 16 + c * 2);
        unsigned u1 = *(const unsigned*)(ip + (size_t)s1 * 16 + c * 2);
        float wc0 = w0, wc1 = w1;
        int i2 = i + 16;
        e0 = i2 + g; e1 = i2 + 8 + g;
        s0 = __builtin_nontemporal_load(csr_src + b0 + (e0 < n ? e0 : n - 1));
        s1 = __builtin_nontemporal_load(csr_src + b0 + (e1 < n ? e1 : n - 1));
        w0 = (e0 < n) ? 1.f : 0.f;
        w1 = (e1 < n) ? 1.f : 0.f;
        acc += unpk(u0) * wc0;
        acc += unpk(u1) * wc1;
      }
    }
#pragma unroll
    for (int o = 8; o < 64; o <<= 1) {
      acc.x += __shfl_xor(acc.x, o, 64);
      acc.y += __shfl_xor(acc.y, o, 64);
    }
    if (g == 0) {
      unsigned r = (unsigned)f2bf(dv * acc.x) | ((unsigned)f2bf(dv * acc.y) << 16);
      *(unsigned*)(op + (size_t)v * 16 + c * 2) = r;
    }
  }
}

// ---------- width-40 aggregation + bias + log_softmax (layer 3) ----------
__global__ __launch_bounds__(256) void k_agg40(
    const unsigned short* __restrict__ P, const int* __restrict__ offs,
    const int* __restrict__ csr_src, const float* __restrict__ dinv,
    const unsigned short* __restrict__ bias, float* __restrict__ outp) {
  const int lane = threadIdx.x & 63;
  const int g = lane >> 5, l = lane & 31;
  const bool act = l < 20;
  const int v = (blockIdx.x * 256 + threadIdx.x) >> 6;
  if (v >= NNODES) return;

  float dv = dinv[v];
  f32x2 a = (f32x2)0.f;
  if (act && g == 0) a = unpk(*(const unsigned*)(P + (size_t)v * 40 + l * 2));
  int b0 = offs[v];
  int n = offs[v + 1] - b0;
  if (n > 0) {
    int s[4];
    float wg[4];
#pragma unroll
    for (int j = 0; j < 4; ++j) {
      int e = j * 2 + g;
      int ec = (e < n) ? e : (n - 1);
      s[j] = csr_src[b0 + ec];
      wg[j] = (e < n) ? 1.f : 0.f;
    }
    for (int i = 0; i < n; i += 8) {
      unsigned gu[4];
#pragma unroll
      for (int j = 0; j < 4; ++j)
        gu[j] = act ? *(const unsigned*)(P + (size_t)s[j] * 40 + l * 2) : 0u;
      float wc[4];
#pragma unroll
      for (int j = 0; j < 4; ++j) wc[j] = wg[j];
      int i2 = i + 8;
#pragma unroll
      for (int j = 0; j < 4; ++j) {
        int e = i2 + j * 2 + g;
        int ec = (e < n) ? e : (n - 1);
        s[j] = csr_src[b0 + ec];
        wg[j] = (e < n) ? 1.f : 0.f;
      }
#pragma unroll
      for (int j = 0; j < 4; ++j) a += unpk(gu[j]) * wc[j];
    }
  }
  a.x += __shfl_xor(a.x, 32, 64);
  a.y += __shfl_xor(a.y, 32, 64);
  float a0 = 0.f, a1 = 0.f;
  if (act) {
    a0 = dv * a.x + bf2f((unsigned)bias[l * 2]);
    a1 = dv * a.y + bf2f((unsigned)bias[l * 2 + 1]);
  }
  float m = act ? fmaxf(a0, a1) : -1e30f;
#pragma unroll
  for (int o = 16; o > 0; o >>= 1) m = fmaxf(m, __shfl_xor(m, o, 32));
  float ss = act ? (expf(a0 - m) + expf(a1 - m)) : 0.f;
#pragma unroll
  for (int o = 16; o > 0; o >>= 1) ss += __shfl_xor(ss, o, 32);
  float ls = logf(ss) + m;
  if (act && g == 0) {
    float2 o2;
    o2.x = a0 - ls;
    o2.y = a1 - ls;
    *(float2*)(outp + (size_t)v * 160 + l * 2) = o2;
  }
}

// ---------- GEMM bodies on caller-provided LDS ----------
// A-operand staging: PLANES ? [K/16][N][16] : row-major [N][K]
template <int K, bool PLANES>
__device__ __forceinline__ uint4 ldA(const unsigned short* __restrict__ A, int gr, int cc) {
  if (PLANES)
    return *(const uint4*)(A + (size_t)(cc >> 4) * PLANE_ELT + (size_t)gr * 16 + (cc & 15));
  return *(const uint4*)(A + (size_t)gr * K + cc);
}

// mlp: out = relu(A@W + b)[*dinv] -> PLANE layout; 128x128 tile at (m0,c0); A planes
template <int K, bool SCALE>
__device__ __forceinline__ void mlp_body(
    char* smem, int m0, int c0,
    const unsigned short* __restrict__ A, const unsigned short* __restrict__ WT,
    const unsigned short* __restrict__ bias, unsigned short* __restrict__ out,
    const float* __restrict__ dinv) {
  short* As = (short*)smem;             // 128*40
  short* Bs = (short*)(smem + 10240);   // 128*40
  const int t = threadIdx.x;
  const int lane = t & 63, wv = t >> 6;
  const int mw = (wv >> 1) * 64, nw = (wv & 1) * 64;
  const int lr = lane & 15, lq = lane >> 4;

  f32x4 acc[4][4];
#pragma unroll
  for (int i = 0; i < 4; ++i)
#pragma unroll
    for (int j = 0; j < 4; ++j) acc[i][j] = (f32x4)0.f;

  for (int kc = 0; kc < K; kc += 32) {
    __syncthreads();
#pragma unroll
    for (int it = 0; it < 2; ++it) {
      int idx = t + it * 256;
      int row = idx >> 2, seg = idx & 3;
      uint4 u = make_uint4(0, 0, 0, 0);
      int gr = m0 + row;
      if (gr < NNODES) u = ldA<K, true>(A, gr, kc + seg * 8);
      *(uint4*)&As[row * 40 + seg * 8] = u;
      uint4 v = *(const uint4*)(WT + (size_t)(c0 + row) * K + kc + seg * 8);
      *(uint4*)&Bs[row * 40 + seg * 8] = v;
    }
    __syncthreads();
    bf16x8 af[4], bfr[4];
#pragma unroll
    for (int i = 0; i < 4; ++i)
      af[i] = *(const bf16x8*)&As[(mw + 16 * i + lr) * 40 + lq * 8];
#pragma unroll
    for (int j = 0; j < 4; ++j)
      bfr[j] = *(const bf16x8*)&Bs[(nw + 16 * j + lr) * 40 + lq * 8];
#pragma unroll
    for (int i = 0; i < 4; ++i)
#pragma unroll
      for (int j = 0; j < 4; ++j)
        acc[i][j] = __builtin_amdgcn_mfma_f32_16x16x32_bf16(af[i], bfr[j], acc[i][j], 0, 0, 0);
  }

  float bv[4];
#pragma unroll
  for (int j = 0; j < 4; ++j) bv[j] = bf2f((unsigned)bias[c0 + nw + 16 * j + lr]);
#pragma unroll
  for (int i = 0; i < 4; ++i) {
    int rbase = m0 + mw + 16 * i + lq * 4;
#pragma unroll
    for (int r = 0; r < 4; ++r) {
      int row = rbase + r;
      if (row < NNODES) {
        float s = SCALE ? dinv[row] : 1.f;
#pragma unroll
        for (int j = 0; j < 4; ++j) {
          int col = c0 + nw + 16 * j + lr;
          float v = fmaxf(acc[i][j][r] + bv[j], 0.f) * s;
          out[(size_t)(col >> 4) * PLANE_ELT + (size_t)row * 16 + (col & 15)] = f2bf(v);
        }
      }
    }
  }
}

// exit: (A@We) 128-row tile; SOFTMAX -> f32 log-softmax rows, else P*dinv bf16 [N][40]
template <int K, bool SOFTMAX, bool PLANES>
__device__ __forceinline__ void exit_body(
    char* smem, int m0,
    const unsigned short* __restrict__ A, const unsigned short* __restrict__ WT,
    const unsigned short* __restrict__ bias, float* __restrict__ outp,
    unsigned short* __restrict__ Pout, const float* __restrict__ dinv) {
  constexpr int KP = K + 8;
  short* As = (short*)smem;             // 128*40
  short* Bs = (short*)(smem + 10240);   // 48*KP
  const int t = threadIdx.x;
  const int lane = t & 63, wv = t >> 6;
  const int mw = wv * 32;
  const int lr = lane & 15, lq = lane >> 4;

  for (int idx = t; idx < 48 * (K / 8); idx += 256) {
    int row = idx / (K / 8), seg = idx % (K / 8);
    uint4 w = *(const uint4*)(WT + (size_t)row * K + seg * 8);
    *(uint4*)&Bs[row * KP + seg * 8] = w;
  }

  f32x4 acc[2][3];
#pragma unroll
  for (int i = 0; i < 2; ++i)
#pragma unroll
    for (int j = 0; j < 3; ++j) acc[i][j] = (f32x4)0.f;

  for (int kc = 0; kc < K; kc += 32) {
    __syncthreads();
#pragma unroll
    for (int it = 0; it < 2; ++it) {
      int idx = t + it * 256;
      int row = idx >> 2, seg = idx & 3;
      uint4 u = make_uint4(0, 0, 0, 0);
      int gr = m0 + row;
      if (gr < NNODES) u = ldA<K, PLANES>(A, gr, kc + seg * 8);
      *(uint4*)&As[row * 40 + seg * 8] = u;
    }
    __syncthreads();
    bf16x8 af[2], bfr[3];
#pragma unroll
    for (int i = 0; i < 2; ++i)
      af[i] = *(const bf16x8*)&As[(mw + 16 * i + lr) * 40 + lq * 8];
#pragma unroll
    for (int j = 0; j < 3; ++j)
      bfr[j] = *(const bf16x8*)&Bs[(16 * j + lr) * KP + kc + lq * 8];
#pragma unroll
    for (int i = 0; i < 2; ++i)
#pragma unroll
      for (int j = 0; j < 3; ++j)
        acc[i][j] = __builtin_amdgcn_mfma_f32_16x16x32_bf16(af[i], bfr[j], acc[i][j], 0, 0, 0);
  }

  if (SOFTMAX) {
    float bv0 = bf2f((unsigned)bias[lr]);
    float bv1 = bf2f((unsigned)bias[16 + lr]);
    float bv2 = (lr < 8) ? bf2f((unsigned)bias[32 + lr]) : 0.f;
#pragma unroll
    for (int i = 0; i < 2; ++i) {
#pragma unroll
      for (int r = 0; r < 4; ++r) {
        int row = m0 + mw + 16 * i + lq * 4 + r;
        float v0 = acc[i][0][r] + bv0;
        float v1 = acc[i][1][r] + bv1;
        float v2 = (lr < 8) ? (acc[i][2][r] + bv2) : -1e30f;
        float m = fmaxf(fmaxf(v0, v1), v2);
#pragma unroll
        for (int o = 8; o > 0; o >>= 1) m = fmaxf(m, __shfl_xor(m, o, 16));
        float ss = expf(v0 - m) + expf(v1 - m) + ((lr < 8) ? expf(v2 - m) : 0.f);
#pragma unroll
        for (int o = 8; o > 0; o >>= 1) ss += __shfl_xor(ss, o, 16);
        float ls = logf(ss) + m;
        if (row < NNODES) {
          outp[(size_t)row * 160 + lr] = v0 - ls;
          outp[(size_t)row * 160 + 16 + lr] = v1 - ls;
          if (lr < 8) outp[(size_t)row * 160 + 32 + lr] = v2 - ls;
        }
      }
    }
  } else {
#pragma unroll
    for (int i = 0; i < 2; ++i) {
#pragma unroll
      for (int r = 0; r < 4; ++r) {
        int row = m0 + mw + 16 * i + lq * 4 + r;
        if (row < NNODES) {
          float s = dinv[row];
          Pout[(size_t)row * 40 + lr] = f2bf(acc[i][0][r] * s);
          Pout[(size_t)row * 40 + 16 + lr] = f2bf(acc[i][1][r] * s);
          if (lr < 8) Pout[(size_t)row * 40 + 32 + lr] = f2bf(acc[i][2][r] * s);
        }
      }
    }
  }
}

// ---------- kernels wrapping the bodies ----------
template <int K> struct ExitSM { static constexpr int B = 10240 + 48 * (K + 8) * 2; };

__global__ __launch_bounds__(256) void k_exit0(
    const unsigned short* __restrict__ A, const unsigned short* __restrict__ WT,
    const unsigned short* __restrict__ bias, float* __restrict__ outp,
    const float* __restrict__ dinv) {
  __shared__ __align__(16) char smem[ExitSM<128>::B];
  exit_body<128, true, false>(smem, blockIdx.x * 128, A, WT, bias, outp, nullptr, dinv);
}

__global__ __launch_bounds__(256) void k_exit3(
    const unsigned short* __restrict__ A, const unsigned short* __restrict__ WT,
    unsigned short* __restrict__ Pout, const float* __restrict__ dinv) {
  __shared__ __align__(16) char smem[ExitSM<256>::B];
  exit_body<256, false, true>(smem, blockIdx.x * 128, A, WT, nullptr, nullptr, Pout, dinv);
}

// heterogeneous: blocks [0,1564) mlp (128x128 tiles, 2 col-halves);
// blocks [1564, 2346) exit+softmax. Both read the same plane-layout A.
template <int K, bool MLPSCALE>
__global__ __launch_bounds__(256) void k_exit_mlp(
    const unsigned short* __restrict__ A,
    const unsigned short* __restrict__ WTmlp, const unsigned short* __restrict__ bmlp,
    unsigned short* __restrict__ outmlp,
    const unsigned short* __restrict__ WTex, const unsigned short* __restrict__ bex,
    float* __restrict__ outp, const float* __restrict__ dinv) {
  constexpr int SM = (ExitSM<K>::B > 20480) ? ExitSM<K>::B : 20480;
  __shared__ __align__(16) char smem[SM];
  int bid = blockIdx.x;
  if (bid < 1564) {
    mlp_body<K, MLPSCALE>(smem, (bid >> 1) * 128, (bid & 1) * 128, A, WTmlp, bmlp, outmlp, dinv);
  } else {
    exit_body<K, true, true>(smem, (bid - 1564) * 128, A, WTex, bex, outp, nullptr, dinv);
  }
}

// ---------- launch ----------
extern "C" void kernel_launch(void* const* d_in, const int* in_sizes, int n_in,
                              void* d_out, int out_size, void* d_ws, size_t ws_size,
                              hipStream_t stream) {
  const void* x_raw   = d_in[0];
  const int* ei       = (const int*)d_in[1];
  float* out          = (float*)d_out;

  char* ws = (char*)d_ws;
  int*   flags    = (int*)(ws + 0);
  int*   bcnt     = (int*)(ws + 4096);
  int*   gcur     = (int*)(ws + 8192);
  int*   bbase    = (int*)(ws + 12288);
  float* dinv     = (float*)(ws + 524288);
  int*   offs     = (int*)(ws + 1048576);
  int*   csr_src  = (int*)(ws + 2097152);   // 6.4 MB
  int*   stage    = (int*)(ws + 8650752);   // 6.4 MB
  unsigned short* xb = (unsigned short*)(ws + 16777216);   // N*128 bf16 row-major (reused as P)
  unsigned short* wb = (unsigned short*)(ws + 45088768);   // weights
  unsigned short* hA = (unsigned short*)(ws + 48234496);   // 16 planes (51.2 MB)
  unsigned short* hB = (unsigned short*)(ws + 100663296);  // 16 planes (51.2 MB)
  unsigned short* xs = hB;  // 8 prescaled x-planes alias hB (dead until mlp128 writes)
  unsigned short* P  = xb;

  unsigned short* bc0 = wb + 32768;
  unsigned short* bc1 = wb + 98560;
  unsigned short* be0 = wb + 103936;
  unsigned short* be1 = wb + 109096;
  unsigned short* be2 = wb + 119376;
  unsigned short* be3 = wb + 129656;
  unsigned short* WTc0  = wb + 131072;  // 256 x 128
  unsigned short* WTc1  = wb + 163840;  // 256 x 256
  unsigned short* WT40e0 = wb + 229376; // 48 x 128
  unsigned short* WT40e1 = wb + 235520; // 48 x 128
  unsigned short* WT40e2 = wb + 241664; // 48 x 256
  unsigned short* WT40e3 = wb + 253952; // 48 x 256

  dim3 B(256);
  // bucketed CSR build (bcnt block 0 also probes x dtype -> flags[0])
  k_zero<<<dim3(4), B, 0, stream>>>(bcnt, NBKT);
  k_bcnt<<<dim3(391), B, 0, stream>>>(ei, bcnt, (const unsigned*)x_raw, flags);
  k_bscan2<<<dim3(1), dim3(64), 0, stream>>>(bcnt, bbase, gcur);
  k_bstage<<<dim3(391), B, 0, stream>>>(ei, gcur, stage);
  k_bplace<<<dim3(NBKT), B, 0, stream>>>(stage, bbase, offs, dinv, csr_src);

  // convert x (row-major + prescaled planes), biases, raw-W transposes
  CvtP p;
  const int bsrc[7] = {0, 3, 5, 9, 11, 13, 15};
  unsigned short* bdst[7] = {xb, bc0, bc1, be0, be1, be2, be3};
  const int bn[7] = {NNODES * 128, 256, 256, 40, 40, 40, 40};
  for (int i = 0; i < 7; ++i) { p.src[i] = d_in[bsrc[i]]; p.dst[i] = bdst[i]; p.n[i] = bn[i]; }
  const int wsrc[6] = {2, 4, 8, 10, 12, 14};
  unsigned short* wdst[6] = {WTc0, WTc1, WT40e0, WT40e1, WT40e2, WT40e3};
  for (int i = 0; i < 6; ++i) { p.W[i] = d_in[wsrc[i]]; p.WT[i] = wdst[i]; }
  k_cvt<<<dim3(1024, 8), B, 0, stream>>>(p, flags, dinv, xs);

  // layer 0: exit on x (row-major)
  k_exit0<<<dim3(782), B, 0, stream>>>(xb, WT40e0, be0, out + 0 * 40, dinv);
  // h1 = agg(xs): 8 planes, XCD-pinned
  k_aggp<8><<<dim3(20000), B, 0, stream>>>(xs, hA, offs, csr_src, dinv);
  // exit1(hA) || hB = relu(hA Wc0 + bc0)*dinv  (16 planes, prescaled)
  k_exit_mlp<128, true><<<dim3(2346), B, 0, stream>>>(hA, WTc0, bc0, hB,
                                                      WT40e1, be1, out + 1 * 40, dinv);
  // h2 = agg(hB): 16 planes, XCD-pinned
  k_aggp<16><<<dim3(40000), B, 0, stream>>>(hB, hA, offs, csr_src, dinv);
  // exit2(hA) || hB = relu(hA Wc1 + bc1)
  k_exit_mlp<256, false><<<dim3(2346), B, 0, stream>>>(hA, WTc1, bc1, hB,
                                                       WT40e2, be2, out + 2 * 40, dinv);
  // layer 3 push-through: P = (hB @ We3) * dinv  (row-major [N][40])
  k_exit3<<<dim3(782), B, 0, stream>>>(hB, WT40e3, P, dinv);
  k_agg40<<<dim3(25000), B, 0, stream>>>(P, offs, csr_src, dinv, be3, out + 3 * 40);
}

// Round 8
// 743.891 us; speedup vs baseline: 1.4031x; 1.4031x over previous
//
#include <hip/hip_runtime.h>

#define NNODES 100000
#define NEDGES 1600000
#define NBKT 782          // buckets of 128 nodes: 782*128 = 100096 >= NNODES

typedef __attribute__((ext_vector_type(8))) short bf16x8;
typedef __attribute__((ext_vector_type(4))) float f32x4;
typedef __attribute__((ext_vector_type(2))) float f32x2;

// ---------- bf16 helpers ----------
__device__ __forceinline__ float bf2f(unsigned v) {
  union { unsigned u; float f; } x; x.u = v << 16; return x.f;
}
__device__ __forceinline__ unsigned short f2bf(float f) {
  union { float f; unsigned u; } x; x.f = f;
  unsigned r = x.u + 0x7fffu + ((x.u >> 16) & 1u);
  return (unsigned short)(r >> 16);
}
__device__ __forceinline__ f32x2 unpk(unsigned u) {
  union { unsigned q; float f; } lo, hi;
  lo.q = u << 16; hi.q = u & 0xffff0000u;
  f32x2 r; r.x = lo.f; r.y = hi.f; return r;
}
__device__ __forceinline__ unsigned short ldcv(const void* p, int i, int f32) {
  return f32 ? f2bf(((const float*)p)[i]) : ((const unsigned short*)p)[i];
}
__device__ __forceinline__ int detect_i64(const int* __restrict__ ei) {
  int lane = threadIdx.x & 63;
  int hv = ei[2 * lane + 1];
  unsigned long long nz = __ballot(hv != 0);
  return (__popcll(nz) < 4) ? 1 : 0;
}
__device__ __forceinline__ int edge_at(const int* __restrict__ ei, int j, int i64) {
  return i64 ? ei[2 * j] : ei[j];
}

__global__ void k_zero(int* __restrict__ p, int n) {
  int v = blockIdx.x * blockDim.x + threadIdx.x;
  if (v < n) p[v] = 0;
}

// ---------- bucketed CSR build (no global per-edge atomics) ----------
__global__ __launch_bounds__(256) void k_bcnt(const int* __restrict__ ei,
                                              int* __restrict__ bcnt,
                                              const unsigned* __restrict__ xw,
                                              int* __restrict__ flags) {
  __shared__ int h[NBKT];
  __shared__ int cF;
  int t = threadIdx.x;
  for (int i = t; i < NBKT; i += 256) h[i] = 0;
  if (blockIdx.x == 0 && t == 0) cF = 0;
  __syncthreads();
  if (blockIdx.x == 0) {
    int hf = 0;
    for (int i = t; i < 2048; i += 256) {
      unsigned lo = xw[i] & 0xffffu;
      unsigned e = (lo >> 7) & 0xffu;
      if (e >= 0xC0u) hf++;
    }
    atomicAdd(&cF, hf);
  }
  int i64 = detect_i64(ei);
  int e0 = blockIdx.x * 4096;
#pragma unroll
  for (int k = 0; k < 16; ++k) {
    int e = e0 + t + k * 256;
    if (e < NEDGES) {
      int d = edge_at(ei, NEDGES + e, i64);
      if ((unsigned)d < NNODES) atomicAdd(&h[d >> 7], 1);
    }
  }
  __syncthreads();
  for (int i = t; i < NBKT; i += 256)
    if (h[i]) atomicAdd(&bcnt[i], h[i]);
  if (blockIdx.x == 0 && t == 0) flags[0] = (cF > 32) ? 1 : 0;
}

__global__ void k_bscan2(const int* __restrict__ bcnt, int* __restrict__ bbase,
                         int* __restrict__ gcur) {
  int l = threadIdx.x;  // 64 lanes
  int v[13];
  int s = 0;
#pragma unroll
  for (int k = 0; k < 13; ++k) {
    int j = l * 13 + k;
    v[k] = (j < NBKT) ? bcnt[j] : 0;
    s += v[k];
  }
  int x = s;
#pragma unroll
  for (int o = 1; o < 64; o <<= 1) {
    int y = __shfl_up(x, o, 64);
    if (l >= o) x += y;
  }
  int excl = x - s;
#pragma unroll
  for (int k = 0; k < 13; ++k) {
    int j = l * 13 + k;
    if (j < NBKT) { bbase[j] = excl; gcur[j] = excl; }
    excl += v[k];
  }
  if (l == 63) bbase[NBKT] = x;
}

__global__ __launch_bounds__(256) void k_bstage(const int* __restrict__ ei,
                                                int* __restrict__ gcur,
                                                int* __restrict__ stage) {
  __shared__ int h[NBKT];
  __shared__ int base[NBKT];
  int t = threadIdx.x;
  for (int i = t; i < NBKT; i += 256) h[i] = 0;
  __syncthreads();
  int i64 = detect_i64(ei);
  int e0 = blockIdx.x * 4096;
  int bkt[16], lp[16], rec[16];
#pragma unroll
  for (int k = 0; k < 16; ++k) {
    bkt[k] = -1;
    int e = e0 + t + k * 256;
    if (e < NEDGES) {
      int d = edge_at(ei, NEDGES + e, i64);
      if ((unsigned)d < NNODES) {
        int s = edge_at(ei, e, i64);
        if ((unsigned)s >= NNODES) s = NNODES - 1;
        bkt[k] = d >> 7;
        rec[k] = ((d & 127) << 17) | s;
        lp[k] = atomicAdd(&h[bkt[k]], 1);
      }
    }
  }
  __syncthreads();
  for (int i = t; i < NBKT; i += 256)
    base[i] = h[i] ? atomicAdd(&gcur[i], h[i]) : 0;
  __syncthreads();
#pragma unroll
  for (int k = 0; k < 16; ++k)
    if (bkt[k] >= 0) stage[base[bkt[k]] + lp[k]] = rec[k];
}

__global__ __launch_bounds__(256) void k_bplace(const int* __restrict__ stage,
                                                const int* __restrict__ bbase,
                                                int* __restrict__ offs,
                                                float* __restrict__ dinv,
                                                int* __restrict__ csr_src) {
  __shared__ int h[128];
  __shared__ int cur[128];
  int b = blockIdx.x;
  int t = threadIdx.x;
  int n0 = b * 128;
  int NN = NNODES - n0; if (NN > 128) NN = 128;
  int s0 = bbase[b], s1 = bbase[b + 1];
  int cnt = s1 - s0;
  if (t < 128) h[t] = 0;
  __syncthreads();
  for (int i = t; i < cnt; i += 256) {
    int rec = stage[s0 + i];
    atomicAdd(&h[rec >> 17], 1);
  }
  __syncthreads();
  if (t < 64) {
    int a = h[2 * t], c = h[2 * t + 1];
    int s = a + c;
    int x = s;
#pragma unroll
    for (int o = 1; o < 64; o <<= 1) {
      int y = __shfl_up(x, o, 64);
      if (t >= o) x += y;
    }
    int excl = s0 + x - s;
    cur[2 * t] = excl;
    cur[2 * t + 1] = excl + a;
    if (2 * t < NN) {
      offs[n0 + 2 * t] = excl;
      dinv[n0 + 2 * t] = rsqrtf((float)a + 1.0f);
    }
    if (2 * t + 1 < NN) {
      offs[n0 + 2 * t + 1] = excl + a;
      dinv[n0 + 2 * t + 1] = rsqrtf((float)c + 1.0f);
    }
  }
  if (b == NBKT - 1 && t == 0) offs[NNODES] = s1;
  __syncthreads();
  for (int i = t; i < cnt; i += 256) {
    int rec = stage[s0 + i];
    int pos = atomicAdd(&cur[rec >> 17], 1);
    csr_src[pos] = rec & 0x1FFFF;
  }
}

// ---------- canonicalize + weight prep, one dispatch ----------
struct CvtP {
  const void* src[7];
  unsigned short* dst[7];
  int n[7];
  const void* W[6];
  unsigned short* WT[6];
};

__global__ void k_cvt(CvtP p, const int* __restrict__ flags,
                      const float* __restrict__ dinv, unsigned short* __restrict__ xs) {
  int a = blockIdx.y;
  int f32 = flags[0];
  if (a < 7) {
    int n = p.n[a];
    const float* sf = (const float*)p.src[a];
    const unsigned short* sb = (const unsigned short*)p.src[a];
    unsigned short* d = p.dst[a];
    for (int i = blockIdx.x * blockDim.x + threadIdx.x; i < n; i += gridDim.x * blockDim.x) {
      if (a == 0) {
        float v = f32 ? sf[i] : bf2f((unsigned)sb[i]);
        d[i] = f32 ? f2bf(v) : sb[i];
        xs[i] = f2bf(v * dinv[i >> 7]);
      } else {
        d[i] = f32 ? f2bf(sf[i]) : sb[i];
      }
    }
  } else {
    int g = blockIdx.x * 256 + threadIdx.x;
    if (g < 32768) {
      int k = g >> 8, c = g & 255;
      p.WT[0][c * 128 + k] = ldcv(p.W[0], g, f32);
    } else if (g < 98304) {
      int l = g - 32768; int k = l >> 8, c = l & 255;
      p.WT[1][c * 256 + k] = ldcv(p.W[1], l, f32);
    } else if (g < 104448) {
      int l = g - 98304; int c = l >> 7, k = l & 127;
      p.WT[2][l] = (c < 40) ? ldcv(p.W[2], k * 40 + c, f32) : (unsigned short)0;
    } else if (g < 110592) {
      int l = g - 104448; int c = l >> 7, k = l & 127;
      p.WT[3][l] = (c < 40) ? ldcv(p.W[3], k * 40 + c, f32) : (unsigned short)0;
    } else if (g < 122880) {
      int l = g - 110592; int c = l >> 8, k = l & 255;
      p.WT[4][l] = (c < 40) ? ldcv(p.W[4], k * 40 + c, f32) : (unsigned short)0;
    } else if (g < 135168) {
      int l = g - 122880; int c = l >> 8, k = l & 255;
      p.WT[5][l] = (c < 40) ? ldcv(p.W[5], k * 40 + c, f32) : (unsigned short)0;
    }
  }
}

__device__ __forceinline__ void accp(f32x2 (&acc)[4], uint4 u, float w) {
  acc[0] += unpk(u.x) * w;
  acc[1] += unpk(u.y) * w;
  acc[2] += unpk(u.z) * w;
  acc[3] += unpk(u.w) * w;
}

// ---------- fused layer kernel: agg(64 rows)->LDS -> mlp GEMM + exit GEMM ----------
// hin: prescaled input [N][K] row-major. A_lds holds h_agg rows (x dinv[v]).
// mlp: outmlp = relu(A @ Wc + bc) [*dinv]  (row-major [N][256])
// exit: outp rows = log_softmax(A @ We + be)
// Grid: GRID blocks x TILES row-tiles of 64, all resident (3 blocks/CU cap by LDS).
template <int K, bool SCALE, int TILES, int GRID>
__global__ __launch_bounds__(256) void k_fused(
    const unsigned short* __restrict__ hin,
    const unsigned short* __restrict__ WTmlp, const unsigned short* __restrict__ bmlp,
    unsigned short* __restrict__ outmlp,
    const unsigned short* __restrict__ WTex, const unsigned short* __restrict__ bex,
    float* __restrict__ outp,
    const int* __restrict__ offs, const int* __restrict__ csr_src,
    const float* __restrict__ dinv) {
  constexpr int KP = K + 8;
  constexpr int LPR = K / 8;    // lanes per row (16 B each)
  constexpr int R = 64 / LPR;   // rows per gather instr
  constexpr int EPB = 16;
  constexpr int NB = EPB / R;
  __shared__ __align__(16) short A[64 * KP];
  __shared__ __align__(16) short Bs[128 * 40];
  const int t = threadIdx.x;
  const int lane = t & 63, wvi = t >> 6;
  const int g = lane / LPR, l = lane % LPR;
  const int lr = lane & 15, lq = lane >> 4;

  for (int tile = 0; tile < TILES; ++tile) {
    int m0 = (blockIdx.x + tile * GRID) * 64;
    if (m0 >= NNODES) break;
    __syncthreads();  // protect A from previous tile's readers

    // ---- phase 1: aggregate 64 rows into LDS ----
    for (int w = 0; w < 16; ++w) {
      int v = m0 + wvi * 16 + w;
      if (v >= NNODES) break;
      float dv = dinv[v];
      uint4 su = *(const uint4*)(hin + (size_t)v * K + l * 8);
      f32x2 acc[4];
#pragma unroll
      for (int k = 0; k < 4; ++k) acc[k] = (f32x2)0.f;
      accp(acc, su, (g == 0) ? 1.f : 0.f);

      int b0 = offs[v];
      int n = offs[v + 1] - b0;
      if (n > 0) {
        int s[NB];
        float wg[NB];
#pragma unroll
        for (int j = 0; j < NB; ++j) {
          int e = j * R + g;
          s[j] = csr_src[b0 + (e < n ? e : n - 1)];
          wg[j] = (e < n) ? 1.f : 0.f;
        }
        for (int i = 0; i < n; i += EPB) {
          uint4 gu[NB];
#pragma unroll
          for (int j = 0; j < NB; ++j)
            gu[j] = *(const uint4*)(hin + (size_t)s[j] * K + l * 8);
          float wc[NB];
#pragma unroll
          for (int j = 0; j < NB; ++j) wc[j] = wg[j];
          int i2 = i + EPB;
#pragma unroll
          for (int j = 0; j < NB; ++j) {
            int e = i2 + j * R + g;
            s[j] = csr_src[b0 + (e < n ? e : n - 1)];
            wg[j] = (e < n) ? 1.f : 0.f;
          }
#pragma unroll
          for (int j = 0; j < NB; ++j) accp(acc, gu[j], wc[j]);
        }
      }
      float a8[8];
#pragma unroll
      for (int k = 0; k < 4; ++k) { a8[2 * k] = acc[k].x; a8[2 * k + 1] = acc[k].y; }
#pragma unroll
      for (int k = 0; k < 8; ++k) {
#pragma unroll
        for (int o = LPR; o < 64; o <<= 1) a8[k] += __shfl_xor(a8[k], o, 64);
      }
      if (g == 0) {
        uint4 ov;
        ov.x = (unsigned)f2bf(dv * a8[0]) | ((unsigned)f2bf(dv * a8[1]) << 16);
        ov.y = (unsigned)f2bf(dv * a8[2]) | ((unsigned)f2bf(dv * a8[3]) << 16);
        ov.z = (unsigned)f2bf(dv * a8[4]) | ((unsigned)f2bf(dv * a8[5]) << 16);
        ov.w = (unsigned)f2bf(dv * a8[6]) | ((unsigned)f2bf(dv * a8[7]) << 16);
        *(uint4*)&A[(v - m0) * KP + l * 8] = ov;
      }
    }

    // ---- phase 2: mlp GEMM (64 rows x 256 cols, two 128-col tiles) ----
    {
      const int mw = (wvi >> 1) * 32, nw = (wvi & 1) * 64;
#pragma unroll
      for (int c0 = 0; c0 < 256; c0 += 128) {
        f32x4 acc[2][4];
#pragma unroll
        for (int i = 0; i < 2; ++i)
#pragma unroll
          for (int j = 0; j < 4; ++j) acc[i][j] = (f32x4)0.f;
        for (int kc = 0; kc < K; kc += 32) {
          __syncthreads();
#pragma unroll
          for (int it = 0; it < 2; ++it) {
            int idx = t + it * 256;
            int row = idx >> 2, seg = idx & 3;
            uint4 u = *(const uint4*)(WTmlp + (size_t)(c0 + row) * K + kc + seg * 8);
            *(uint4*)&Bs[row * 40 + seg * 8] = u;
          }
          __syncthreads();
          bf16x8 af[2], bfr[4];
#pragma unroll
          for (int i = 0; i < 2; ++i)
            af[i] = *(const bf16x8*)&A[(mw + 16 * i + lr) * KP + kc + lq * 8];
#pragma unroll
          for (int j = 0; j < 4; ++j)
            bfr[j] = *(const bf16x8*)&Bs[(nw + 16 * j + lr) * 40 + lq * 8];
#pragma unroll
          for (int i = 0; i < 2; ++i)
#pragma unroll
            for (int j = 0; j < 4; ++j)
              acc[i][j] = __builtin_amdgcn_mfma_f32_16x16x32_bf16(af[i], bfr[j], acc[i][j], 0, 0, 0);
        }
        float bv[4];
#pragma unroll
        for (int j = 0; j < 4; ++j) bv[j] = bf2f((unsigned)bmlp[c0 + nw + 16 * j + lr]);
#pragma unroll
        for (int i = 0; i < 2; ++i) {
          int rbase = m0 + mw + 16 * i + lq * 4;
#pragma unroll
          for (int r = 0; r < 4; ++r) {
            int row = rbase + r;
            if (row < NNODES) {
              float s = SCALE ? dinv[row] : 1.f;
#pragma unroll
              for (int j = 0; j < 4; ++j) {
                int col = c0 + nw + 16 * j + lr;
                float v = fmaxf(acc[i][j][r] + bv[j], 0.f) * s;
                outmlp[(size_t)row * 256 + col] = f2bf(v);
              }
            }
          }
        }
      }
    }

    // ---- phase 3: exit GEMM + log_softmax (64 rows, 16 per wave) ----
    {
      const int mw = wvi * 16;
      f32x4 acc[3];
#pragma unroll
      for (int j = 0; j < 3; ++j) acc[j] = (f32x4)0.f;
      for (int kc = 0; kc < K; kc += 32) {
        __syncthreads();
        if (t < 192) {
          int row = t >> 2, seg = t & 3;
          uint4 u = *(const uint4*)(WTex + (size_t)row * K + kc + seg * 8);
          *(uint4*)&Bs[row * 40 + seg * 8] = u;
        }
        __syncthreads();
        bf16x8 af = *(const bf16x8*)&A[(mw + lr) * KP + kc + lq * 8];
        bf16x8 bfr[3];
#pragma unroll
        for (int j = 0; j < 3; ++j)
          bfr[j] = *(const bf16x8*)&Bs[(16 * j + lr) * 40 + lq * 8];
#pragma unroll
        for (int j = 0; j < 3; ++j)
          acc[j] = __builtin_amdgcn_mfma_f32_16x16x32_bf16(af, bfr[j], acc[j], 0, 0, 0);
      }
      float bv0 = bf2f((unsigned)bex[lr]);
      float bv1 = bf2f((unsigned)bex[16 + lr]);
      float bv2 = (lr < 8) ? bf2f((unsigned)bex[32 + lr]) : 0.f;
#pragma unroll
      for (int r = 0; r < 4; ++r) {
        int row = m0 + mw + lq * 4 + r;
        float v0 = acc[0][r] + bv0;
        float v1 = acc[1][r] + bv1;
        float v2 = (lr < 8) ? (acc[2][r] + bv2) : -1e30f;
        float m = fmaxf(fmaxf(v0, v1), v2);
#pragma unroll
        for (int o = 8; o > 0; o >>= 1) m = fmaxf(m, __shfl_xor(m, o, 16));
        float ss = expf(v0 - m) + expf(v1 - m) + ((lr < 8) ? expf(v2 - m) : 0.f);
#pragma unroll
        for (int o = 8; o > 0; o >>= 1) ss += __shfl_xor(ss, o, 16);
        float ls = logf(ss) + m;
        if (row < NNODES) {
          outp[(size_t)row * 160 + lr] = v0 - ls;
          outp[(size_t)row * 160 + 16 + lr] = v1 - ls;
          if (lr < 8) outp[(size_t)row * 160 + 32 + lr] = v2 - ls;
        }
      }
    }
  }
}

// ---------- standalone exit GEMM (128-row tiles, hoisted B-panel) ----------
// SOFTMAX: f32 log-softmax rows. !SOFTMAX: P = (A@We)*dinv, [N][48] bf16, cols 40..47 = 0.
template <int K, bool SOFTMAX>
__global__ __launch_bounds__(256) void k_exit(
    const unsigned short* __restrict__ Ain, const unsigned short* __restrict__ WT,
    const unsigned short* __restrict__ bias, float* __restrict__ outp,
    unsigned short* __restrict__ Pout, const float* __restrict__ dinv) {
  constexpr int KP = K + 8;
  __shared__ __align__(16) short As[128 * 40];
  __shared__ __align__(16) short Bsp[48 * KP];
  const int t = threadIdx.x;
  const int lane = t & 63, wv = t >> 6;
  const int m0 = blockIdx.x * 128;
  const int mw = wv * 32;
  const int lr = lane & 15, lq = lane >> 4;

  for (int idx = t; idx < 48 * (K / 8); idx += 256) {
    int row = idx / (K / 8), seg = idx % (K / 8);
    uint4 w = *(const uint4*)(WT + (size_t)row * K + seg * 8);
    *(uint4*)&Bsp[row * KP + seg * 8] = w;
  }

  f32x4 acc[2][3];
#pragma unroll
  for (int i = 0; i < 2; ++i)
#pragma unroll
    for (int j = 0; j < 3; ++j) acc[i][j] = (f32x4)0.f;

  for (int kc = 0; kc < K; kc += 32) {
    __syncthreads();
#pragma unroll
    for (int it = 0; it < 2; ++it) {
      int idx = t + it * 256;
      int row = idx >> 2, seg = idx & 3;
      uint4 u = make_uint4(0, 0, 0, 0);
      int gr = m0 + row;
      if (gr < NNODES) u = *(const uint4*)(Ain + (size_t)gr * K + kc + seg * 8);
      *(uint4*)&As[row * 40 + seg * 8] = u;
    }
    __syncthreads();
    bf16x8 af[2], bfr[3];
#pragma unroll
    for (int i = 0; i < 2; ++i)
      af[i] = *(const bf16x8*)&As[(mw + 16 * i + lr) * 40 + lq * 8];
#pragma unroll
    for (int j = 0; j < 3; ++j)
      bfr[j] = *(const bf16x8*)&Bsp[(16 * j + lr) * KP + kc + lq * 8];
#pragma unroll
    for (int i = 0; i < 2; ++i)
#pragma unroll
      for (int j = 0; j < 3; ++j)
        acc[i][j] = __builtin_amdgcn_mfma_f32_16x16x32_bf16(af[i], bfr[j], acc[i][j], 0, 0, 0);
  }

  if (SOFTMAX) {
    float bv0 = bf2f((unsigned)bias[lr]);
    float bv1 = bf2f((unsigned)bias[16 + lr]);
    float bv2 = (lr < 8) ? bf2f((unsigned)bias[32 + lr]) : 0.f;
#pragma unroll
    for (int i = 0; i < 2; ++i) {
#pragma unroll
      for (int r = 0; r < 4; ++r) {
        int row = m0 + mw + 16 * i + lq * 4 + r;
        float v0 = acc[i][0][r] + bv0;
        float v1 = acc[i][1][r] + bv1;
        float v2 = (lr < 8) ? (acc[i][2][r] + bv2) : -1e30f;
        float m = fmaxf(fmaxf(v0, v1), v2);
#pragma unroll
        for (int o = 8; o > 0; o >>= 1) m = fmaxf(m, __shfl_xor(m, o, 16));
        float ss = expf(v0 - m) + expf(v1 - m) + ((lr < 8) ? expf(v2 - m) : 0.f);
#pragma unroll
        for (int o = 8; o > 0; o >>= 1) ss += __shfl_xor(ss, o, 16);
        float ls = logf(ss) + m;
        if (row < NNODES) {
          outp[(size_t)row * 160 + lr] = v0 - ls;
          outp[(size_t)row * 160 + 16 + lr] = v1 - ls;
          if (lr < 8) outp[(size_t)row * 160 + 32 + lr] = v2 - ls;
        }
      }
    }
  } else {
#pragma unroll
    for (int i = 0; i < 2; ++i) {
#pragma unroll
      for (int r = 0; r < 4; ++r) {
        int row = m0 + mw + 16 * i + lq * 4 + r;
        if (row < NNODES) {
          float s = dinv[row];
          Pout[(size_t)row * 48 + lr] = f2bf(acc[i][0][r] * s);
          Pout[(size_t)row * 48 + 16 + lr] = f2bf(acc[i][1][r] * s);
          Pout[(size_t)row * 48 + 32 + lr] =
              (lr < 8) ? f2bf(acc[i][2][r] * s) : (unsigned short)0;
        }
      }
    }
  }
}

// ---------- width-40 aggregation + bias + log_softmax (layer 3) ----------
// P [N][48] prescaled (cols 40..47 zero). Wave per node: 5 edge slots x 12 lanes
// of 8 B (4 cols each), 10 edges per 2 gather instrs, index prefetch.
__global__ __launch_bounds__(256) void k_agg40(
    const unsigned short* __restrict__ P, const int* __restrict__ offs,
    const int* __restrict__ csr_src, const float* __restrict__ dinv,
    const unsigned short* __restrict__ bias, float* __restrict__ outp) {
  const int lane = threadIdx.x & 63;
  const int g = lane / 12;   // edge slot 0..4 (lanes 60..63 inactive)
  const int l = lane % 12;   // 4-col group
  const bool act = lane < 60;
  const int v = (blockIdx.x * 256 + threadIdx.x) >> 6;
  if (v >= NNODES) return;

  float dv = dinv[v];
  f32x2 a0 = (f32x2)0.f, a1 = (f32x2)0.f;
  if (act && g == 0) {
    uint2 su = *(const uint2*)(P + (size_t)v * 48 + l * 4);
    a0 = unpk(su.x);
    a1 = unpk(su.y);
  }
  int b0 = offs[v];
  int n = offs[v + 1] - b0;
  if (n > 0) {
    int e0 = g, e1 = 5 + g;
    int s0 = csr_src[b0 + (e0 < n ? e0 : n - 1)];
    int s1 = csr_src[b0 + (e1 < n ? e1 : n - 1)];
    float w0 = (act && e0 < n) ? 1.f : 0.f;
    float w1 = (act && e1 < n) ? 1.f : 0.f;
    for (int i = 0; i < n; i += 10) {
      uint2 u0 = *(const uint2*)(P + (size_t)s0 * 48 + l * 4);
      uint2 u1 = *(const uint2*)(P + (size_t)s1 * 48 + l * 4);
      float wc0 = w0, wc1 = w1;
      int i2 = i + 10;
      e0 = i2 + g; e1 = i2 + 5 + g;
      s0 = csr_src[b0 + (e0 < n ? e0 : n - 1)];
      s1 = csr_src[b0 + (e1 < n ? e1 : n - 1)];
      w0 = (act && e0 < n) ? 1.f : 0.f;
      w1 = (act && e1 < n) ? 1.f : 0.f;
      a0 += unpk(u0.x) * wc0;
      a1 += unpk(u0.y) * wc0;
      a0 += unpk(u1.x) * wc1;
      a1 += unpk(u1.y) * wc1;
    }
  }
  // reduce across the 5 edge slots (capture-then-add)
  float sums[4] = {a0.x, a0.y, a1.x, a1.y};
#pragma unroll
  for (int k = 0; k < 4; ++k) {
    float x = sums[k];
    float x1 = __shfl(x, lane + 12, 64);
    float x2 = __shfl(x, lane + 24, 64);
    float x3 = __shfl(x, lane + 36, 64);
    float x4 = __shfl(x, lane + 48, 64);
    sums[k] = x + x1 + x2 + x3 + x4;
  }
  // lanes 0..9 hold cols 4l..4l+3 (exactly 40 cols)
  bool ol = (g == 0) && (l < 10);
  float c0v = ol ? (dv * sums[0] + bf2f((unsigned)bias[l * 4 + 0])) : -1e30f;
  float c1v = ol ? (dv * sums[1] + bf2f((unsigned)bias[l * 4 + 1])) : -1e30f;
  float c2v = ol ? (dv * sums[2] + bf2f((unsigned)bias[l * 4 + 2])) : -1e30f;
  float c3v = ol ? (dv * sums[3] + bf2f((unsigned)bias[l * 4 + 3])) : -1e30f;
  float m = fmaxf(fmaxf(c0v, c1v), fmaxf(c2v, c3v));
#pragma unroll
  for (int o = 8; o > 0; o >>= 1) m = fmaxf(m, __shfl_xor(m, o, 16));
  float ss = ol ? (expf(c0v - m) + expf(c1v - m) + expf(c2v - m) + expf(c3v - m)) : 0.f;
#pragma unroll
  for (int o = 8; o > 0; o >>= 1) ss += __shfl_xor(ss, o, 16);
  float ls = logf(ss) + m;
  if (ol) {
    float4 o4;
    o4.x = c0v - ls; o4.y = c1v - ls; o4.z = c2v - ls; o4.w = c3v - ls;
    *(float4*)(outp + (size_t)v * 160 + l * 4) = o4;
  }
}

// ---------- launch ----------
extern "C" void kernel_launch(void* const* d_in, const int* in_sizes, int n_in,
                              void* d_out, int out_size, void* d_ws, size_t ws_size,
                              hipStream_t stream) {
  const void* x_raw   = d_in[0];
  const int* ei       = (const int*)d_in[1];
  float* out          = (float*)d_out;

  char* ws = (char*)d_ws;
  int*   flags    = (int*)(ws + 0);
  int*   bcnt     = (int*)(ws + 4096);
  int*   gcur     = (int*)(ws + 8192);
  int*   bbase    = (int*)(ws + 12288);
  float* dinv     = (float*)(ws + 524288);
  int*   offs     = (int*)(ws + 1048576);
  int*   csr_src  = (int*)(ws + 2097152);   // 6.4 MB
  int*   stage    = (int*)(ws + 8650752);   // 6.4 MB
  unsigned short* xb = (unsigned short*)(ws + 16777216);   // N*128 bf16 (reused as P [N][48])
  unsigned short* wb = (unsigned short*)(ws + 45088768);   // weights
  unsigned short* hA = (unsigned short*)(ws + 48234496);   // N*256 bf16
  unsigned short* hB = (unsigned short*)(ws + 100663296);  // N*256 bf16
  unsigned short* xs = hB;  // prescaled x aliases hB (dead until F256 mlp writes hB)
  unsigned short* P  = xb;

  unsigned short* bc0 = wb + 32768;
  unsigned short* bc1 = wb + 98560;
  unsigned short* be0 = wb + 103936;
  unsigned short* be1 = wb + 109096;
  unsigned short* be2 = wb + 119376;
  unsigned short* be3 = wb + 129656;
  unsigned short* WTc0  = wb + 131072;  // 256 x 128
  unsigned short* WTc1  = wb + 163840;  // 256 x 256
  unsigned short* WT40e0 = wb + 229376; // 48 x 128
  unsigned short* WT40e1 = wb + 235520; // 48 x 128
  unsigned short* WT40e2 = wb + 241664; // 48 x 256
  unsigned short* WT40e3 = wb + 253952; // 48 x 256

  dim3 B(256);
  // bucketed CSR build (bcnt block 0 also probes x dtype)
  k_zero<<<dim3(4), B, 0, stream>>>(bcnt, NBKT);
  k_bcnt<<<dim3(391), B, 0, stream>>>(ei, bcnt, (const unsigned*)x_raw, flags);
  k_bscan2<<<dim3(1), dim3(64), 0, stream>>>(bcnt, bbase, gcur);
  k_bstage<<<dim3(391), B, 0, stream>>>(ei, gcur, stage);
  k_bplace<<<dim3(NBKT), B, 0, stream>>>(stage, bbase, offs, dinv, csr_src);

  // convert x (+row-major prescaled xs), biases, raw-W transposes
  CvtP p;
  const int bsrc[7] = {0, 3, 5, 9, 11, 13, 15};
  unsigned short* bdst[7] = {xb, bc0, bc1, be0, be1, be2, be3};
  const int bn[7] = {NNODES * 128, 256, 256, 40, 40, 40, 40};
  for (int i = 0; i < 7; ++i) { p.src[i] = d_in[bsrc[i]]; p.dst[i] = bdst[i]; p.n[i] = bn[i]; }
  const int wsrc[6] = {2, 4, 8, 10, 12, 14};
  unsigned short* wdst[6] = {WTc0, WTc1, WT40e0, WT40e1, WT40e2, WT40e3};
  for (int i = 0; i < 6; ++i) { p.W[i] = d_in[wsrc[i]]; p.WT[i] = wdst[i]; }
  k_cvt<<<dim3(1024, 8), B, 0, stream>>>(p, flags, dinv, xs);

  // layer 0: exit on x
  k_exit<128, true><<<dim3(782), B, 0, stream>>>(xb, WT40e0, be0, out + 0 * 40, nullptr, dinv);
  // layer 1 fused: agg(xs) -> LDS -> {exit1 -> out1 ; mlp -> hA (prescaled)}
  k_fused<128, true, 2, 782><<<dim3(782), B, 0, stream>>>(
      xs, WTc0, bc0, hA, WT40e1, be1, out + 1 * 40, offs, csr_src, dinv);
  // layer 2 fused: agg(hA) -> LDS -> {exit2 -> out2 ; mlp -> hB}
  k_fused<256, false, 3, 522><<<dim3(522), B, 0, stream>>>(
      hA, WTc1, bc1, hB, WT40e2, be2, out + 2 * 40, offs, csr_src, dinv);
  // layer 3 push-through: P = (hB @ We3) * dinv, [N][48]
  k_exit<256, false><<<dim3(782), B, 0, stream>>>(hB, WT40e3, nullptr, nullptr, P, dinv);
  k_agg40<<<dim3(25000), B, 0, stream>>>(P, offs, csr_src, dinv, be3, out + 3 * 40);
}

// Round 9
// 644.922 us; speedup vs baseline: 1.6184x; 1.1535x over previous
//
#include <hip/hip_runtime.h>

#define NNODES 100000
#define NEDGES 1600000
#define NBKT 782          // buckets of 128 nodes: 782*128 = 100096 >= NNODES

typedef __attribute__((ext_vector_type(8))) short bf16x8;
typedef __attribute__((ext_vector_type(4))) float f32x4;
typedef __attribute__((ext_vector_type(2))) float f32x2;

// ---------- bf16 helpers ----------
__device__ __forceinline__ float bf2f(unsigned v) {
  union { unsigned u; float f; } x; x.u = v << 16; return x.f;
}
__device__ __forceinline__ unsigned short f2bf(float f) {
  union { float f; unsigned u; } x; x.f = f;
  unsigned r = x.u + 0x7fffu + ((x.u >> 16) & 1u);
  return (unsigned short)(r >> 16);
}
__device__ __forceinline__ f32x2 unpk(unsigned u) {
  union { unsigned q; float f; } lo, hi;
  lo.q = u << 16; hi.q = u & 0xffff0000u;
  f32x2 r; r.x = lo.f; r.y = hi.f; return r;
}
__device__ __forceinline__ unsigned short ldcv(const void* p, int i, int f32) {
  return f32 ? f2bf(((const float*)p)[i]) : ((const unsigned short*)p)[i];
}
__device__ __forceinline__ int detect_i64(const int* __restrict__ ei) {
  int lane = threadIdx.x & 63;
  int hv = ei[2 * lane + 1];
  unsigned long long nz = __ballot(hv != 0);
  return (__popcll(nz) < 4) ? 1 : 0;
}
__device__ __forceinline__ int edge_at(const int* __restrict__ ei, int j, int i64) {
  return i64 ? ei[2 * j] : ei[j];
}

__global__ void k_zero(int* __restrict__ p, int n) {
  int v = blockIdx.x * blockDim.x + threadIdx.x;
  if (v < n) p[v] = 0;
}

// ---------- bucketed CSR build (no global per-edge atomics) ----------
__global__ __launch_bounds__(256) void k_bcnt(const int* __restrict__ ei,
                                              int* __restrict__ bcnt,
                                              const unsigned* __restrict__ xw,
                                              int* __restrict__ flags) {
  __shared__ int h[NBKT];
  __shared__ int cF;
  int t = threadIdx.x;
  for (int i = t; i < NBKT; i += 256) h[i] = 0;
  if (blockIdx.x == 0 && t == 0) cF = 0;
  __syncthreads();
  if (blockIdx.x == 0) {
    int hf = 0;
    for (int i = t; i < 2048; i += 256) {
      unsigned lo = xw[i] & 0xffffu;
      unsigned e = (lo >> 7) & 0xffu;
      if (e >= 0xC0u) hf++;
    }
    atomicAdd(&cF, hf);
  }
  int i64 = detect_i64(ei);
  int e0 = blockIdx.x * 4096;
#pragma unroll
  for (int k = 0; k < 16; ++k) {
    int e = e0 + t + k * 256;
    if (e < NEDGES) {
      int d = edge_at(ei, NEDGES + e, i64);
      if ((unsigned)d < NNODES) atomicAdd(&h[d >> 7], 1);
    }
  }
  __syncthreads();
  for (int i = t; i < NBKT; i += 256)
    if (h[i]) atomicAdd(&bcnt[i], h[i]);
  if (blockIdx.x == 0 && t == 0) flags[0] = (cF > 32) ? 1 : 0;
}

__global__ void k_bscan2(const int* __restrict__ bcnt, int* __restrict__ bbase,
                         int* __restrict__ gcur) {
  int l = threadIdx.x;  // 64 lanes
  int v[13];
  int s = 0;
#pragma unroll
  for (int k = 0; k < 13; ++k) {
    int j = l * 13 + k;
    v[k] = (j < NBKT) ? bcnt[j] : 0;
    s += v[k];
  }
  int x = s;
#pragma unroll
  for (int o = 1; o < 64; o <<= 1) {
    int y = __shfl_up(x, o, 64);
    if (l >= o) x += y;
  }
  int excl = x - s;
#pragma unroll
  for (int k = 0; k < 13; ++k) {
    int j = l * 13 + k;
    if (j < NBKT) { bbase[j] = excl; gcur[j] = excl; }
    excl += v[k];
  }
  if (l == 63) bbase[NBKT] = x;
}

__global__ __launch_bounds__(256) void k_bstage(const int* __restrict__ ei,
                                                int* __restrict__ gcur,
                                                int* __restrict__ stage) {
  __shared__ int h[NBKT];
  __shared__ int base[NBKT];
  int t = threadIdx.x;
  for (int i = t; i < NBKT; i += 256) h[i] = 0;
  __syncthreads();
  int i64 = detect_i64(ei);
  int e0 = blockIdx.x * 4096;
  int bkt[16], lp[16], rec[16];
#pragma unroll
  for (int k = 0; k < 16; ++k) {
    bkt[k] = -1;
    int e = e0 + t + k * 256;
    if (e < NEDGES) {
      int d = edge_at(ei, NEDGES + e, i64);
      if ((unsigned)d < NNODES) {
        int s = edge_at(ei, e, i64);
        if ((unsigned)s >= NNODES) s = NNODES - 1;
        bkt[k] = d >> 7;
        rec[k] = ((d & 127) << 17) | s;
        lp[k] = atomicAdd(&h[bkt[k]], 1);
      }
    }
  }
  __syncthreads();
  for (int i = t; i < NBKT; i += 256)
    base[i] = h[i] ? atomicAdd(&gcur[i], h[i]) : 0;
  __syncthreads();
#pragma unroll
  for (int k = 0; k < 16; ++k)
    if (bkt[k] >= 0) stage[base[bkt[k]] + lp[k]] = rec[k];
}

__global__ __launch_bounds__(256) void k_bplace(const int* __restrict__ stage,
                                                const int* __restrict__ bbase,
                                                int* __restrict__ offs,
                                                float* __restrict__ dinv,
                                                int* __restrict__ csr_src) {
  __shared__ int h[128];
  __shared__ int cur[128];
  int b = blockIdx.x;
  int t = threadIdx.x;
  int n0 = b * 128;
  int NN = NNODES - n0; if (NN > 128) NN = 128;
  int s0 = bbase[b], s1 = bbase[b + 1];
  int cnt = s1 - s0;
  if (t < 128) h[t] = 0;
  __syncthreads();
  for (int i = t; i < cnt; i += 256) {
    int rec = stage[s0 + i];
    atomicAdd(&h[rec >> 17], 1);
  }
  __syncthreads();
  if (t < 64) {
    int a = h[2 * t], c = h[2 * t + 1];
    int s = a + c;
    int x = s;
#pragma unroll
    for (int o = 1; o < 64; o <<= 1) {
      int y = __shfl_up(x, o, 64);
      if (t >= o) x += y;
    }
    int excl = s0 + x - s;
    cur[2 * t] = excl;
    cur[2 * t + 1] = excl + a;
    if (2 * t < NN) {
      offs[n0 + 2 * t] = excl;
      dinv[n0 + 2 * t] = rsqrtf((float)a + 1.0f);
    }
    if (2 * t + 1 < NN) {
      offs[n0 + 2 * t + 1] = excl + a;
      dinv[n0 + 2 * t + 1] = rsqrtf((float)c + 1.0f);
    }
  }
  if (b == NBKT - 1 && t == 0) offs[NNODES] = s1;
  __syncthreads();
  for (int i = t; i < cnt; i += 256) {
    int rec = stage[s0 + i];
    int pos = atomicAdd(&cur[rec >> 17], 1);
    csr_src[pos] = rec & 0x1FFFF;
  }
}

// ---------- canonicalize + weight prep, one dispatch ----------
struct CvtP {
  const void* src[7];
  unsigned short* dst[7];
  int n[7];
  const void* W[6];
  unsigned short* WT[6];
};

__global__ void k_cvt(CvtP p, const int* __restrict__ flags,
                      const float* __restrict__ dinv, unsigned short* __restrict__ xs) {
  int a = blockIdx.y;
  int f32 = flags[0];
  if (a < 7) {
    int n = p.n[a];
    const float* sf = (const float*)p.src[a];
    const unsigned short* sb = (const unsigned short*)p.src[a];
    unsigned short* d = p.dst[a];
    for (int i = blockIdx.x * blockDim.x + threadIdx.x; i < n; i += gridDim.x * blockDim.x) {
      if (a == 0) {
        float v = f32 ? sf[i] : bf2f((unsigned)sb[i]);
        d[i] = f32 ? f2bf(v) : sb[i];
        xs[i] = f2bf(v * dinv[i >> 7]);
      } else {
        d[i] = f32 ? f2bf(sf[i]) : sb[i];
      }
    }
  } else {
    int g = blockIdx.x * 256 + threadIdx.x;
    if (g < 32768) {
      int k = g >> 8, c = g & 255;
      p.WT[0][c * 128 + k] = ldcv(p.W[0], g, f32);
    } else if (g < 98304) {
      int l = g - 32768; int k = l >> 8, c = l & 255;
      p.WT[1][c * 256 + k] = ldcv(p.W[1], l, f32);
    } else if (g < 104448) {
      int l = g - 98304; int c = l >> 7, k = l & 127;
      p.WT[2][l] = (c < 40) ? ldcv(p.W[2], k * 40 + c, f32) : (unsigned short)0;
    } else if (g < 110592) {
      int l = g - 104448; int c = l >> 7, k = l & 127;
      p.WT[3][l] = (c < 40) ? ldcv(p.W[3], k * 40 + c, f32) : (unsigned short)0;
    } else if (g < 122880) {
      int l = g - 110592; int c = l >> 8, k = l & 255;
      p.WT[4][l] = (c < 40) ? ldcv(p.W[4], k * 40 + c, f32) : (unsigned short)0;
    } else if (g < 135168) {
      int l = g - 122880; int c = l >> 8, k = l & 255;
      p.WT[5][l] = (c < 40) ? ldcv(p.W[5], k * 40 + c, f32) : (unsigned short)0;
    }
  }
}

__device__ __forceinline__ void accp(f32x2 (&acc)[4], uint4 u, float w) {
  acc[0] += unpk(u.x) * w;
  acc[1] += unpk(u.y) * w;
  acc[2] += unpk(u.z) * w;
  acc[3] += unpk(u.w) * w;
}

// ---------- column-partitioned aggregation, XCD-pinned slices ----------
// Input [N][D] row-major, prescaled by dinv[src]. Array split into P vertical
// slices of DP=D/P >= 64 cols (128 B/row-slice, 16 B/lane). Slice p is
// processed ONLY by blocks with (blockIdx%8)%P == p -> each XCD's L2 touches
// size/P bytes; total fetch = 8*size/P (vs 8*size unpartitioned).
// Wave = 1 node x 1 slice: 8 lanes/row, 8 rows (edges) per gather instr,
// 16 edges/batch with index prefetch. out[v] = dinv[v]*(edges + self).
template <int D, int P>
__global__ __launch_bounds__(256) void k_aggp(
    const unsigned short* __restrict__ hin, unsigned short* __restrict__ hout,
    const int* __restrict__ offs, const int* __restrict__ csr_src,
    const float* __restrict__ dinv) {
  constexpr int DP = D / P;      // slice width (cols), 64
  constexpr int LPR = DP / 8;    // lanes per row-slice (16 B each) = 8
  constexpr int R = 64 / LPR;    // rows per gather instr = 8
  constexpr int NB = 2;          // gather instrs per batch
  constexpr int EPB = NB * R;    // 16 edges per batch
  const int b = blockIdx.x;
  const int x = b & 7;                              // XCD (round-robin)
  const int part = x % P;                           // slice owned by this XCD
  const int nodeblk = (b >> 3) * (8 / P) + x / P;   // [0, 25000)
  const int lane = threadIdx.x & 63;
  const int wvi = threadIdx.x >> 6;
  const int g = lane / LPR;      // edge slot [0,8)
  const int l = lane % LPR;      // 16B chunk within slice
  const int v = nodeblk * 4 + wvi;
  if (v >= NNODES) return;

  const size_t cbase = (size_t)part * DP + l * 8;
  float dv = dinv[v];
  uint4 su = *(const uint4*)(hin + (size_t)v * D + cbase);
  f32x2 acc[4];
#pragma unroll
  for (int k = 0; k < 4; ++k) acc[k] = (f32x2)0.f;
  accp(acc, su, (g == 0) ? 1.f : 0.f);

  int b0 = offs[v];
  int n = offs[v + 1] - b0;
  if (n > 0) {
    int s[NB];
    float wg[NB];
#pragma unroll
    for (int j = 0; j < NB; ++j) {
      int e = j * R + g;
      s[j] = csr_src[b0 + (e < n ? e : n - 1)];
      wg[j] = (e < n) ? 1.f : 0.f;
    }
    for (int i = 0; i < n; i += EPB) {
      uint4 gu[NB];
#pragma unroll
      for (int j = 0; j < NB; ++j)
        gu[j] = *(const uint4*)(hin + (size_t)s[j] * D + cbase);
      float wc[NB];
#pragma unroll
      for (int j = 0; j < NB; ++j) wc[j] = wg[j];
      int i2 = i + EPB;
#pragma unroll
      for (int j = 0; j < NB; ++j) {
        int e = i2 + j * R + g;
        s[j] = csr_src[b0 + (e < n ? e : n - 1)];
        wg[j] = (e < n) ? 1.f : 0.f;
      }
#pragma unroll
      for (int j = 0; j < NB; ++j) accp(acc, gu[j], wc[j]);
    }
  }
  float a8[8];
#pragma unroll
  for (int k = 0; k < 4; ++k) { a8[2 * k] = acc[k].x; a8[2 * k + 1] = acc[k].y; }
#pragma unroll
  for (int k = 0; k < 8; ++k) {
#pragma unroll
    for (int o = LPR; o < 64; o <<= 1) a8[k] += __shfl_xor(a8[k], o, 64);
  }
  if (g == 0) {
    uint4 ov;
    ov.x = (unsigned)f2bf(dv * a8[0]) | ((unsigned)f2bf(dv * a8[1]) << 16);
    ov.y = (unsigned)f2bf(dv * a8[2]) | ((unsigned)f2bf(dv * a8[3]) << 16);
    ov.z = (unsigned)f2bf(dv * a8[4]) | ((unsigned)f2bf(dv * a8[5]) << 16);
    ov.w = (unsigned)f2bf(dv * a8[6]) | ((unsigned)f2bf(dv * a8[7]) << 16);
    *(uint4*)(hout + (size_t)v * D + cbase) = ov;
  }
}

// ---------- width-40 aggregation + bias + log_softmax (layer 3) ----------
__global__ __launch_bounds__(256) void k_agg40(
    const unsigned short* __restrict__ P, const int* __restrict__ offs,
    const int* __restrict__ csr_src, const float* __restrict__ dinv,
    const unsigned short* __restrict__ bias, float* __restrict__ outp) {
  const int lane = threadIdx.x & 63;
  const int g = lane >> 5, l = lane & 31;
  const bool act = l < 20;
  const int v = (blockIdx.x * 256 + threadIdx.x) >> 6;
  if (v >= NNODES) return;

  float dv = dinv[v];
  f32x2 a = (f32x2)0.f;
  if (act && g == 0) a = unpk(*(const unsigned*)(P + (size_t)v * 40 + l * 2));
  int b0 = offs[v];
  int n = offs[v + 1] - b0;
  if (n > 0) {
    int s[4];
    float wg[4];
#pragma unroll
    for (int j = 0; j < 4; ++j) {
      int e = j * 2 + g;
      int ec = (e < n) ? e : (n - 1);
      s[j] = csr_src[b0 + ec];
      wg[j] = (e < n) ? 1.f : 0.f;
    }
    for (int i = 0; i < n; i += 8) {
      unsigned gu[4];
#pragma unroll
      for (int j = 0; j < 4; ++j)
        gu[j] = act ? *(const unsigned*)(P + (size_t)s[j] * 40 + l * 2) : 0u;
      float wc[4];
#pragma unroll
      for (int j = 0; j < 4; ++j) wc[j] = wg[j];
      int i2 = i + 8;
#pragma unroll
      for (int j = 0; j < 4; ++j) {
        int e = i2 + j * 2 + g;
        int ec = (e < n) ? e : (n - 1);
        s[j] = csr_src[b0 + ec];
        wg[j] = (e < n) ? 1.f : 0.f;
      }
#pragma unroll
      for (int j = 0; j < 4; ++j) a += unpk(gu[j]) * wc[j];
    }
  }
  a.x += __shfl_xor(a.x, 32, 64);
  a.y += __shfl_xor(a.y, 32, 64);
  float a0 = 0.f, a1 = 0.f;
  if (act) {
    a0 = dv * a.x + bf2f((unsigned)bias[l * 2]);
    a1 = dv * a.y + bf2f((unsigned)bias[l * 2 + 1]);
  }
  float m = act ? fmaxf(a0, a1) : -1e30f;
#pragma unroll
  for (int o = 16; o > 0; o >>= 1) m = fmaxf(m, __shfl_xor(m, o, 32));
  float ss = act ? (expf(a0 - m) + expf(a1 - m)) : 0.f;
#pragma unroll
  for (int o = 16; o > 0; o >>= 1) ss += __shfl_xor(ss, o, 32);
  float ls = logf(ss) + m;
  if (act && g == 0) {
    float2 o2;
    o2.x = a0 - ls;
    o2.y = a1 - ls;
    *(float2*)(outp + (size_t)v * 160 + l * 2) = o2;
  }
}

// ---------- GEMM bodies on caller-provided LDS ----------
template <int K, bool SCALE>
__device__ __forceinline__ void mlp_body(
    char* smem, int m0, int c0,
    const unsigned short* __restrict__ A, const unsigned short* __restrict__ WT,
    const unsigned short* __restrict__ bias, unsigned short* __restrict__ out,
    const float* __restrict__ dinv) {
  short* As = (short*)smem;             // 128*40
  short* Bs = (short*)(smem + 10240);   // 128*40
  const int t = threadIdx.x;
  const int lane = t & 63, wv = t >> 6;
  const int mw = (wv >> 1) * 64, nw = (wv & 1) * 64;
  const int lr = lane & 15, lq = lane >> 4;

  f32x4 acc[4][4];
#pragma unroll
  for (int i = 0; i < 4; ++i)
#pragma unroll
    for (int j = 0; j < 4; ++j) acc[i][j] = (f32x4)0.f;

  for (int kc = 0; kc < K; kc += 32) {
    __syncthreads();
#pragma unroll
    for (int it = 0; it < 2; ++it) {
      int idx = t + it * 256;
      int row = idx >> 2, seg = idx & 3;
      uint4 u = make_uint4(0, 0, 0, 0);
      int gr = m0 + row;
      if (gr < NNODES) u = *(const uint4*)(A + (size_t)gr * K + kc + seg * 8);
      *(uint4*)&As[row * 40 + seg * 8] = u;
      uint4 v = *(const uint4*)(WT + (size_t)(c0 + row) * K + kc + seg * 8);
      *(uint4*)&Bs[row * 40 + seg * 8] = v;
    }
    __syncthreads();
    bf16x8 af[4], bfr[4];
#pragma unroll
    for (int i = 0; i < 4; ++i)
      af[i] = *(const bf16x8*)&As[(mw + 16 * i + lr) * 40 + lq * 8];
#pragma unroll
    for (int j = 0; j < 4; ++j)
      bfr[j] = *(const bf16x8*)&Bs[(nw + 16 * j + lr) * 40 + lq * 8];
#pragma unroll
    for (int i = 0; i < 4; ++i)
#pragma unroll
      for (int j = 0; j < 4; ++j)
        acc[i][j] = __builtin_amdgcn_mfma_f32_16x16x32_bf16(af[i], bfr[j], acc[i][j], 0, 0, 0);
  }

  float bv[4];
#pragma unroll
  for (int j = 0; j < 4; ++j) bv[j] = bf2f((unsigned)bias[c0 + nw + 16 * j + lr]);
#pragma unroll
  for (int i = 0; i < 4; ++i) {
    int rbase = m0 + mw + 16 * i + lq * 4;
#pragma unroll
    for (int r = 0; r < 4; ++r) {
      int row = rbase + r;
      if (row < NNODES) {
        float s = SCALE ? dinv[row] : 1.f;
#pragma unroll
        for (int j = 0; j < 4; ++j) {
          int col = c0 + nw + 16 * j + lr;
          float v = fmaxf(acc[i][j][r] + bv[j], 0.f) * s;
          out[(size_t)row * 256 + col] = f2bf(v);
        }
      }
    }
  }
}

template <int K, bool SOFTMAX>
__device__ __forceinline__ void exit_body(
    char* smem, int m0,
    const unsigned short* __restrict__ A, const unsigned short* __restrict__ WT,
    const unsigned short* __restrict__ bias, float* __restrict__ outp,
    unsigned short* __restrict__ Pout, const float* __restrict__ dinv) {
  constexpr int KP = K + 8;
  short* As = (short*)smem;             // 128*40
  short* Bs = (short*)(smem + 10240);   // 48*KP
  const int t = threadIdx.x;
  const int lane = t & 63, wv = t >> 6;
  const int mw = wv * 32;
  const int lr = lane & 15, lq = lane >> 4;

  for (int idx = t; idx < 48 * (K / 8); idx += 256) {
    int row = idx / (K / 8), seg = idx % (K / 8);
    uint4 w = *(const uint4*)(WT + (size_t)row * K + seg * 8);
    *(uint4*)&Bs[row * KP + seg * 8] = w;
  }

  f32x4 acc[2][3];
#pragma unroll
  for (int i = 0; i < 2; ++i)
#pragma unroll
    for (int j = 0; j < 3; ++j) acc[i][j] = (f32x4)0.f;

  for (int kc = 0; kc < K; kc += 32) {
    __syncthreads();
#pragma unroll
    for (int it = 0; it < 2; ++it) {
      int idx = t + it * 256;
      int row = idx >> 2, seg = idx & 3;
      uint4 u = make_uint4(0, 0, 0, 0);
      int gr = m0 + row;
      if (gr < NNODES) u = *(const uint4*)(A + (size_t)gr * K + kc + seg * 8);
      *(uint4*)&As[row * 40 + seg * 8] = u;
    }
    __syncthreads();
    bf16x8 af[2], bfr[3];
#pragma unroll
    for (int i = 0; i < 2; ++i)
      af[i] = *(const bf16x8*)&As[(mw + 16 * i + lr) * 40 + lq * 8];
#pragma unroll
    for (int j = 0; j < 3; ++j)
      bfr[j] = *(const bf16x8*)&Bs[(16 * j + lr) * KP + kc + lq * 8];
#pragma unroll
    for (int i = 0; i < 2; ++i)
#pragma unroll
      for (int j = 0; j < 3; ++j)
        acc[i][j] = __builtin_amdgcn_mfma_f32_16x16x32_bf16(af[i], bfr[j], acc[i][j], 0, 0, 0);
  }

  if (SOFTMAX) {
    float bv0 = bf2f((unsigned)bias[lr]);
    float bv1 = bf2f((unsigned)bias[16 + lr]);
    float bv2 = (lr < 8) ? bf2f((unsigned)bias[32 + lr]) : 0.f;
#pragma unroll
    for (int i = 0; i < 2; ++i) {
#pragma unroll
      for (int r = 0; r < 4; ++r) {
        int row = m0 + mw + 16 * i + lq * 4 + r;
        float v0 = acc[i][0][r] + bv0;
        float v1 = acc[i][1][r] + bv1;
        float v2 = (lr < 8) ? (acc[i][2][r] + bv2) : -1e30f;
        float m = fmaxf(fmaxf(v0, v1), v2);
#pragma unroll
        for (int o = 8; o > 0; o >>= 1) m = fmaxf(m, __shfl_xor(m, o, 16));
        float ss = expf(v0 - m) + expf(v1 - m) + ((lr < 8) ? expf(v2 - m) : 0.f);
#pragma unroll
        for (int o = 8; o > 0; o >>= 1) ss += __shfl_xor(ss, o, 16);
        float ls = logf(ss) + m;
        if (row < NNODES) {
          outp[(size_t)row * 160 + lr] = v0 - ls;
          outp[(size_t)row * 160 + 16 + lr] = v1 - ls;
          if (lr < 8) outp[(size_t)row * 160 + 32 + lr] = v2 - ls;
        }
      }
    }
  } else {
#pragma unroll
    for (int i = 0; i < 2; ++i) {
#pragma unroll
      for (int r = 0; r < 4; ++r) {
        int row = m0 + mw + 16 * i + lq * 4 + r;
        if (row < NNODES) {
          float s = dinv[row];
          Pout[(size_t)row * 40 + lr] = f2bf(acc[i][0][r] * s);
          Pout[(size_t)row * 40 + 16 + lr] = f2bf(acc[i][1][r] * s);
          if (lr < 8) Pout[(size_t)row * 40 + 32 + lr] = f2bf(acc[i][2][r] * s);
        }
      }
    }
  }
}

// ---------- kernels wrapping the bodies ----------
template <int K> struct ExitSM { static constexpr int B = 10240 + 48 * (K + 8) * 2; };

__global__ __launch_bounds__(256) void k_exit0(
    const unsigned short* __restrict__ A, const unsigned short* __restrict__ WT,
    const unsigned short* __restrict__ bias, float* __restrict__ outp,
    const float* __restrict__ dinv) {
  __shared__ __align__(16) char smem[ExitSM<128>::B];
  exit_body<128, true>(smem, blockIdx.x * 128, A, WT, bias, outp, nullptr, dinv);
}

__global__ __launch_bounds__(256) void k_exit3(
    const unsigned short* __restrict__ A, const unsigned short* __restrict__ WT,
    unsigned short* __restrict__ Pout, const float* __restrict__ dinv) {
  __shared__ __align__(16) char smem[ExitSM<256>::B];
  exit_body<256, false>(smem, blockIdx.x * 128, A, WT, nullptr, nullptr, Pout, dinv);
}

// heterogeneous: blocks [0,1564) mlp (128x128 tiles, 2 col-halves);
// blocks [1564, 2346) exit+softmax. Both read the same A.
template <int K, bool MLPSCALE>
__global__ __launch_bounds__(256) void k_exit_mlp(
    const unsigned short* __restrict__ A,
    const unsigned short* __restrict__ WTmlp, const unsigned short* __restrict__ bmlp,
    unsigned short* __restrict__ outmlp,
    const unsigned short* __restrict__ WTex, const unsigned short* __restrict__ bex,
    float* __restrict__ outp, const float* __restrict__ dinv) {
  constexpr int SM = (ExitSM<K>::B > 20480) ? ExitSM<K>::B : 20480;
  __shared__ __align__(16) char smem[SM];
  int bid = blockIdx.x;
  if (bid < 1564) {
    mlp_body<K, MLPSCALE>(smem, (bid >> 1) * 128, (bid & 1) * 128, A, WTmlp, bmlp, outmlp, dinv);
  } else {
    exit_body<K, true>(smem, (bid - 1564) * 128, A, WTex, bex, outp, nullptr, dinv);
  }
}

// ---------- launch ----------
extern "C" void kernel_launch(void* const* d_in, const int* in_sizes, int n_in,
                              void* d_out, int out_size, void* d_ws, size_t ws_size,
                              hipStream_t stream) {
  const void* x_raw   = d_in[0];
  const int* ei       = (const int*)d_in[1];
  float* out          = (float*)d_out;

  char* ws = (char*)d_ws;
  int*   flags    = (int*)(ws + 0);
  int*   bcnt     = (int*)(ws + 4096);
  int*   gcur     = (int*)(ws + 8192);
  int*   bbase    = (int*)(ws + 12288);
  float* dinv     = (float*)(ws + 524288);
  int*   offs     = (int*)(ws + 1048576);
  int*   csr_src  = (int*)(ws + 2097152);   // 6.4 MB
  int*   stage    = (int*)(ws + 8650752);   // 6.4 MB
  unsigned short* xb = (unsigned short*)(ws + 16777216);   // N*128 bf16 (reused as P)
  unsigned short* wb = (unsigned short*)(ws + 45088768);   // weights
  unsigned short* hA = (unsigned short*)(ws + 48234496);   // N*256 bf16
  unsigned short* hB = (unsigned short*)(ws + 100663296);  // N*256 bf16
  unsigned short* xs = hB;  // prescaled x aliases hB (dead until mlp128 writes it)
  unsigned short* P  = xb;

  unsigned short* bc0 = wb + 32768;
  unsigned short* bc1 = wb + 98560;
  unsigned short* be0 = wb + 103936;
  unsigned short* be1 = wb + 109096;
  unsigned short* be2 = wb + 119376;
  unsigned short* be3 = wb + 129656;
  unsigned short* WTc0  = wb + 131072;  // 256 x 128
  unsigned short* WTc1  = wb + 163840;  // 256 x 256
  unsigned short* WT40e0 = wb + 229376; // 48 x 128
  unsigned short* WT40e1 = wb + 235520; // 48 x 128
  unsigned short* WT40e2 = wb + 241664; // 48 x 256
  unsigned short* WT40e3 = wb + 253952; // 48 x 256

  dim3 B(256);
  // bucketed CSR build (bcnt block 0 also probes x dtype -> flags[0])
  k_zero<<<dim3(4), B, 0, stream>>>(bcnt, NBKT);
  k_bcnt<<<dim3(391), B, 0, stream>>>(ei, bcnt, (const unsigned*)x_raw, flags);
  k_bscan2<<<dim3(1), dim3(64), 0, stream>>>(bcnt, bbase, gcur);
  k_bstage<<<dim3(391), B, 0, stream>>>(ei, gcur, stage);
  k_bplace<<<dim3(NBKT), B, 0, stream>>>(stage, bbase, offs, dinv, csr_src);

  // convert x (+xs prescale), biases, and raw-W transposes in one dispatch
  CvtP p;
  const int bsrc[7] = {0, 3, 5, 9, 11, 13, 15};
  unsigned short* bdst[7] = {xb, bc0, bc1, be0, be1, be2, be3};
  const int bn[7] = {NNODES * 128, 256, 256, 40, 40, 40, 40};
  for (int i = 0; i < 7; ++i) { p.src[i] = d_in[bsrc[i]]; p.dst[i] = bdst[i]; p.n[i] = bn[i]; }
  const int wsrc[6] = {2, 4, 8, 10, 12, 14};
  unsigned short* wdst[6] = {WTc0, WTc1, WT40e0, WT40e1, WT40e2, WT40e3};
  for (int i = 0; i < 6; ++i) { p.W[i] = d_in[wsrc[i]]; p.WT[i] = wdst[i]; }
  k_cvt<<<dim3(1024, 8), B, 0, stream>>>(p, flags, dinv, xs);

  // layer 0: exit on x
  k_exit0<<<dim3(782), B, 0, stream>>>(xb, WT40e0, be0, out + 0 * 40, dinv);
  // h1 = agg(xs): 2 column-slices, XCD-pinned
  k_aggp<128, 2><<<dim3(50000), B, 0, stream>>>(xs, hA, offs, csr_src, dinv);
  // exit1(hA) || hB = relu(hA Wc0 + bc0)*dinv
  k_exit_mlp<128, true><<<dim3(2346), B, 0, stream>>>(hA, WTc0, bc0, hB,
                                                      WT40e1, be1, out + 1 * 40, dinv);
  // h2 = agg(hB): 4 column-slices, XCD-pinned
  k_aggp<256, 4><<<dim3(100000), B, 0, stream>>>(hB, hA, offs, csr_src, dinv);
  // exit2(hA) || hB = relu(hA Wc1 + bc1)
  k_exit_mlp<256, false><<<dim3(2346), B, 0, stream>>>(hA, WTc1, bc1, hB,
                                                       WT40e2, be2, out + 2 * 40, dinv);
  // layer 3 push-through: P = (hB @ We3) * dinv
  k_exit3<<<dim3(782), B, 0, stream>>>(hB, WT40e3, P, dinv);
  k_agg40<<<dim3(25000), B, 0, stream>>>(P, offs, csr_src, dinv, be3, out + 3 * 40);
}

// Round 11
// 623.681 us; speedup vs baseline: 1.6735x; 1.0341x over previous
//
#include <hip/hip_runtime.h>

#define NNODES 100000
#define NEDGES 1600000
#define NBKT 782          // buckets of 128 nodes: 782*128 = 100096 >= NNODES

typedef __attribute__((ext_vector_type(8))) short bf16x8;
typedef __attribute__((ext_vector_type(4))) float f32x4;
typedef __attribute__((ext_vector_type(2))) float f32x2;

// ---------- bf16 helpers ----------
__device__ __forceinline__ float bf2f(unsigned v) {
  union { unsigned u; float f; } x; x.u = v << 16; return x.f;
}
__device__ __forceinline__ unsigned short f2bf(float f) {
  union { float f; unsigned u; } x; x.f = f;
  unsigned r = x.u + 0x7fffu + ((x.u >> 16) & 1u);
  return (unsigned short)(r >> 16);
}
__device__ __forceinline__ f32x2 unpk(unsigned u) {
  union { unsigned q; float f; } lo, hi;
  lo.q = u << 16; hi.q = u & 0xffff0000u;
  f32x2 r; r.x = lo.f; r.y = hi.f; return r;
}
__device__ __forceinline__ unsigned short ldcv(const void* p, int i, int f32) {
  return f32 ? f2bf(((const float*)p)[i]) : ((const unsigned short*)p)[i];
}
// per-wave i64 self-detection: high words of int64 node ids are all zero
__device__ __forceinline__ int detect_i64(const int* __restrict__ ei) {
  int lane = threadIdx.x & 63;
  int hv = ei[2 * lane + 1];
  unsigned long long nz = __ballot(hv != 0);
  return (__popcll(nz) < 4) ? 1 : 0;
}
__device__ __forceinline__ int edge_at(const int* __restrict__ ei, int j, int i64) {
  return i64 ? ei[2 * j] : ei[j];
}

__global__ void k_zero(int* __restrict__ p, int n) {
  int v = blockIdx.x * blockDim.x + threadIdx.x;
  if (v < n) p[v] = 0;
}

// ---------- bucketed CSR build (no global per-edge atomics) ----------
// Bucket b = dst >> 7 covers nodes [128b, 128b+128). Record: (dstloc<<17)|src.

// pass 1: per-block LDS histogram; block 0 also probes x dtype -> flags[0]
__global__ __launch_bounds__(256) void k_bcnt(const int* __restrict__ ei,
                                              int* __restrict__ bcnt,
                                              const unsigned* __restrict__ xw,
                                              int* __restrict__ flags) {
  __shared__ int h[NBKT];
  __shared__ int cF;
  int t = threadIdx.x;
  for (int i = t; i < NBKT; i += 256) h[i] = 0;
  if (blockIdx.x == 0 && t == 0) cF = 0;
  __syncthreads();
  if (blockIdx.x == 0) {
    int hf = 0;
    for (int i = t; i < 2048; i += 256) {
      unsigned lo = xw[i] & 0xffffu;
      unsigned e = (lo >> 7) & 0xffu;
      if (e >= 0xC0u) hf++;
    }
    atomicAdd(&cF, hf);
  }
  int i64 = detect_i64(ei);
  int e0 = blockIdx.x * 4096;
#pragma unroll
  for (int k = 0; k < 16; ++k) {
    int e = e0 + t + k * 256;
    if (e < NEDGES) {
      int d = edge_at(ei, NEDGES + e, i64);
      if ((unsigned)d < NNODES) atomicAdd(&h[d >> 7], 1);
    }
  }
  __syncthreads();
  for (int i = t; i < NBKT; i += 256)
    if (h[i]) atomicAdd(&bcnt[i], h[i]);
  if (blockIdx.x == 0 && t == 0) flags[0] = (cF > 32) ? 1 : 0;
}

// scan 782 bucket counts -> bbase[0..782], init gcur
__global__ void k_bscan2(const int* __restrict__ bcnt, int* __restrict__ bbase,
                         int* __restrict__ gcur) {
  int l = threadIdx.x;  // 64 lanes
  int v[13];
  int s = 0;
#pragma unroll
  for (int k = 0; k < 13; ++k) {
    int j = l * 13 + k;
    v[k] = (j < NBKT) ? bcnt[j] : 0;
    s += v[k];
  }
  int x = s;
#pragma unroll
  for (int o = 1; o < 64; o <<= 1) {
    int y = __shfl_up(x, o, 64);
    if (l >= o) x += y;
  }
  int excl = x - s;
#pragma unroll
  for (int k = 0; k < 13; ++k) {
    int j = l * 13 + k;
    if (j < NBKT) { bbase[j] = excl; gcur[j] = excl; }
    excl += v[k];
  }
  if (l == 63) bbase[NBKT] = x;
}

// pass 2: stage records bucket-contiguously (block-aggregated reservations)
__global__ __launch_bounds__(256) void k_bstage(const int* __restrict__ ei,
                                                int* __restrict__ gcur,
                                                int* __restrict__ stage) {
  __shared__ int h[NBKT];
  __shared__ int base[NBKT];
  int t = threadIdx.x;
  for (int i = t; i < NBKT; i += 256) h[i] = 0;
  __syncthreads();
  int i64 = detect_i64(ei);
  int e0 = blockIdx.x * 4096;
  int bkt[16], lp[16], rec[16];
#pragma unroll
  for (int k = 0; k < 16; ++k) {
    bkt[k] = -1;
    int e = e0 + t + k * 256;
    if (e < NEDGES) {
      int d = edge_at(ei, NEDGES + e, i64);
      if ((unsigned)d < NNODES) {
        int s = edge_at(ei, e, i64);
        if ((unsigned)s >= NNODES) s = NNODES - 1;
        bkt[k] = d >> 7;
        rec[k] = ((d & 127) << 17) | s;
        lp[k] = atomicAdd(&h[bkt[k]], 1);
      }
    }
  }
  __syncthreads();
  for (int i = t; i < NBKT; i += 256)
    base[i] = h[i] ? atomicAdd(&gcur[i], h[i]) : 0;
  __syncthreads();
#pragma unroll
  for (int k = 0; k < 16; ++k)
    if (bkt[k] >= 0) stage[base[bkt[k]] + lp[k]] = rec[k];
}

// pass 3: one block per bucket -> offs, dinv, csr_src (LDS atomics only)
__global__ __launch_bounds__(256) void k_bplace(const int* __restrict__ stage,
                                                const int* __restrict__ bbase,
                                                int* __restrict__ offs,
                                                float* __restrict__ dinv,
                                                int* __restrict__ csr_src) {
  __shared__ int h[128];
  __shared__ int cur[128];
  int b = blockIdx.x;
  int t = threadIdx.x;
  int n0 = b * 128;
  int NN = NNODES - n0; if (NN > 128) NN = 128;
  int s0 = bbase[b], s1 = bbase[b + 1];
  int cnt = s1 - s0;
  if (t < 128) h[t] = 0;
  __syncthreads();
  for (int i = t; i < cnt; i += 256) {
    int rec = stage[s0 + i];
    atomicAdd(&h[rec >> 17], 1);
  }
  __syncthreads();
  if (t < 64) {
    int a = h[2 * t], c = h[2 * t + 1];
    int s = a + c;
    int x = s;
#pragma unroll
    for (int o = 1; o < 64; o <<= 1) {
      int y = __shfl_up(x, o, 64);
      if (t >= o) x += y;
    }
    int excl = s0 + x - s;
    cur[2 * t] = excl;
    cur[2 * t + 1] = excl + a;
    if (2 * t < NN) {
      offs[n0 + 2 * t] = excl;
      dinv[n0 + 2 * t] = rsqrtf((float)a + 1.0f);
    }
    if (2 * t + 1 < NN) {
      offs[n0 + 2 * t + 1] = excl + a;
      dinv[n0 + 2 * t + 1] = rsqrtf((float)c + 1.0f);
    }
  }
  if (b == NBKT - 1 && t == 0) offs[NNODES] = s1;
  __syncthreads();
  for (int i = t; i < cnt; i += 256) {
    int rec = stage[s0 + i];
    int pos = atomicAdd(&cur[rec >> 17], 1);
    csr_src[pos] = rec & 0x1FFFF;
  }
}

// ---------- canonicalize + weight prep, one dispatch ----------
// y=0: x -> xb and xs = x*dinv[row] (prescaled); y=1..6: biases; y=7: raw-W transposes.
struct CvtP {
  const void* src[7];
  unsigned short* dst[7];
  int n[7];
  const void* W[6];
  unsigned short* WT[6];
};

__global__ void k_cvt(CvtP p, const int* __restrict__ flags,
                      const float* __restrict__ dinv, unsigned short* __restrict__ xs) {
  int a = blockIdx.y;
  int f32 = flags[0];
  if (a < 7) {
    int n = p.n[a];
    const float* sf = (const float*)p.src[a];
    const unsigned short* sb = (const unsigned short*)p.src[a];
    unsigned short* d = p.dst[a];
    for (int i = blockIdx.x * blockDim.x + threadIdx.x; i < n; i += gridDim.x * blockDim.x) {
      if (a == 0) {
        float v = f32 ? sf[i] : bf2f((unsigned)sb[i]);
        d[i] = f32 ? f2bf(v) : sb[i];
        xs[i] = f2bf(v * dinv[i >> 7]);
      } else {
        d[i] = f32 ? f2bf(sf[i]) : sb[i];
      }
    }
  } else {
    int g = blockIdx.x * 256 + threadIdx.x;
    if (g < 32768) {                       // Wc0[128,256] -> WTc0[256,128]
      int k = g >> 8, c = g & 255;
      p.WT[0][c * 128 + k] = ldcv(p.W[0], g, f32);
    } else if (g < 98304) {                // Wc1[256,256] -> WTc1[256,256]
      int l = g - 32768; int k = l >> 8, c = l & 255;
      p.WT[1][c * 256 + k] = ldcv(p.W[1], l, f32);
    } else if (g < 104448) {               // We0[128,40] -> WT40e0[48,128]
      int l = g - 98304; int c = l >> 7, k = l & 127;
      p.WT[2][l] = (c < 40) ? ldcv(p.W[2], k * 40 + c, f32) : (unsigned short)0;
    } else if (g < 110592) {               // We1
      int l = g - 104448; int c = l >> 7, k = l & 127;
      p.WT[3][l] = (c < 40) ? ldcv(p.W[3], k * 40 + c, f32) : (unsigned short)0;
    } else if (g < 122880) {               // We2[256,40] -> WT40e2[48,256]
      int l = g - 110592; int c = l >> 8, k = l & 255;
      p.WT[4][l] = (c < 40) ? ldcv(p.W[4], k * 40 + c, f32) : (unsigned short)0;
    } else if (g < 135168) {               // We3
      int l = g - 122880; int c = l >> 8, k = l & 255;
      p.WT[5][l] = (c < 40) ? ldcv(p.W[5], k * 40 + c, f32) : (unsigned short)0;
    }
  }
}

__device__ __forceinline__ void accp(f32x2 (&acc)[4], uint4 u, float w) {
  acc[0] += unpk(u.x) * w;
  acc[1] += unpk(u.y) * w;
  acc[2] += unpk(u.z) * w;
  acc[3] += unpk(u.w) * w;
}

// ---------- aggregation: one wave per node, packed fma, index prefetch ----------
// Measured floor (5 variants, r0-r9): FETCH pinned at ~402 MB = 8 XCDs x
// compulsory distinct-row working set (random graph, private L2s), service
// ~3.4-3.9 TB/s. This shape sits on that floor with VALU at ~45%.
template <int D, int EPB>
__global__ __launch_bounds__(256) void k_agg(
    const unsigned short* __restrict__ hin, unsigned short* __restrict__ hout,
    const int* __restrict__ offs, const int* __restrict__ csr_src,
    const float* __restrict__ dinv) {
  constexpr int LPR = D / 8;    // lanes per row (16 B each)
  constexpr int R = 64 / LPR;   // rows per gather instr
  constexpr int NB = EPB / R;   // gather instrs per batch
  const int lane = threadIdx.x & 63;
  const int g = lane / LPR;
  const int l = lane % LPR;
  const int v = (blockIdx.x * 256 + threadIdx.x) >> 6;
  if (v >= NNODES) return;

  float dv = dinv[v];
  const size_t vbase = (size_t)v * D + l * 8;
  uint4 su = *(const uint4*)(hin + vbase);
  f32x2 acc[4];
#pragma unroll
  for (int k = 0; k < 4; ++k) acc[k] = (f32x2)0.f;
  accp(acc, su, (g == 0) ? 1.f : 0.f);

  int b0 = offs[v];
  int n = offs[v + 1] - b0;
  if (n > 0) {
    int s[NB];
    float wg[NB];
#pragma unroll
    for (int j = 0; j < NB; ++j) {
      int e = j * R + g;
      int ec = (e < n) ? e : (n - 1);
      s[j] = csr_src[b0 + ec];
      wg[j] = (e < n) ? 1.f : 0.f;
    }
    for (int i = 0; i < n; i += EPB) {
      uint4 gu[NB];
#pragma unroll
      for (int j = 0; j < NB; ++j)
        gu[j] = *(const uint4*)(hin + (size_t)s[j] * D + l * 8);
      float wc[NB];
#pragma unroll
      for (int j = 0; j < NB; ++j) wc[j] = wg[j];
      int i2 = i + EPB;
#pragma unroll
      for (int j = 0; j < NB; ++j) {
        int e = i2 + j * R + g;
        int ec = (e < n) ? e : (n - 1);
        s[j] = csr_src[b0 + ec];
        wg[j] = (e < n) ? 1.f : 0.f;
      }
#pragma unroll
      for (int j = 0; j < NB; ++j) accp(acc, gu[j], wc[j]);
    }
  }
  float a8[8];
#pragma unroll
  for (int k = 0; k < 4; ++k) { a8[2 * k] = acc[k].x; a8[2 * k + 1] = acc[k].y; }
#pragma unroll
  for (int k = 0; k < 8; ++k) {
#pragma unroll
    for (int o = LPR; o < 64; o <<= 1) a8[k] += __shfl_xor(a8[k], o, 64);
  }
  if (g == 0) {
    uint4 ov;
    ov.x = (unsigned)f2bf(dv * a8[0]) | ((unsigned)f2bf(dv * a8[1]) << 16);
    ov.y = (unsigned)f2bf(dv * a8[2]) | ((unsigned)f2bf(dv * a8[3]) << 16);
    ov.z = (unsigned)f2bf(dv * a8[4]) | ((unsigned)f2bf(dv * a8[5]) << 16);
    ov.w = (unsigned)f2bf(dv * a8[6]) | ((unsigned)f2bf(dv * a8[7]) << 16);
    *(uint4*)(hout + vbase) = ov;
  }
}

// ---------- width-40 aggregation + bias + log_softmax (layer 3) ----------
__global__ __launch_bounds__(256) void k_agg40(
    const unsigned short* __restrict__ P, const int* __restrict__ offs,
    const int* __restrict__ csr_src, const float* __restrict__ dinv,
    const unsigned short* __restrict__ bias, float* __restrict__ outp) {
  const int lane = threadIdx.x & 63;
  const int g = lane >> 5, l = lane & 31;
  const bool act = l < 20;
  const int v = (blockIdx.x * 256 + threadIdx.x) >> 6;
  if (v >= NNODES) return;

  float dv = dinv[v];
  f32x2 a = (f32x2)0.f;
  if (act && g == 0) a = unpk(*(const unsigned*)(P + (size_t)v * 40 + l * 2));
  int b0 = offs[v];
  int n = offs[v + 1] - b0;
  if (n > 0) {
    int s[4];
    float wg[4];
#pragma unroll
    for (int j = 0; j < 4; ++j) {
      int e = j * 2 + g;
      int ec = (e < n) ? e : (n - 1);
      s[j] = csr_src[b0 + ec];
      wg[j] = (e < n) ? 1.f : 0.f;
    }
    for (int i = 0; i < n; i += 8) {
      unsigned gu[4];
#pragma unroll
      for (int j = 0; j < 4; ++j)
        gu[j] = act ? *(const unsigned*)(P + (size_t)s[j] * 40 + l * 2) : 0u;
      float wc[4];
#pragma unroll
      for (int j = 0; j < 4; ++j) wc[j] = wg[j];
      int i2 = i + 8;
#pragma unroll
      for (int j = 0; j < 4; ++j) {
        int e = i2 + j * 2 + g;
        int ec = (e < n) ? e : (n - 1);
        s[j] = csr_src[b0 + ec];
        wg[j] = (e < n) ? 1.f : 0.f;
      }
#pragma unroll
      for (int j = 0; j < 4; ++j) a += unpk(gu[j]) * wc[j];
    }
  }
  a.x += __shfl_xor(a.x, 32, 64);
  a.y += __shfl_xor(a.y, 32, 64);
  float a0 = 0.f, a1 = 0.f;
  if (act) {
    a0 = dv * a.x + bf2f((unsigned)bias[l * 2]);
    a1 = dv * a.y + bf2f((unsigned)bias[l * 2 + 1]);
  }
  float m = act ? fmaxf(a0, a1) : -1e30f;
#pragma unroll
  for (int o = 16; o > 0; o >>= 1) m = fmaxf(m, __shfl_xor(m, o, 32));
  float ss = act ? (expf(a0 - m) + expf(a1 - m)) : 0.f;
#pragma unroll
  for (int o = 16; o > 0; o >>= 1) ss += __shfl_xor(ss, o, 32);
  float ls = logf(ss) + m;
  if (act && g == 0) {
    float2 o2;
    o2.x = a0 - ls;
    o2.y = a1 - ls;
    *(float2*)(outp + (size_t)v * 160 + l * 2) = o2;
  }
}

// ---------- GEMM bodies on caller-provided LDS ----------
// mlp: out = relu(A[N,K] @ W[K,256] + b) [* dinv]; 128x128 tile at (m0,c0)
template <int K, bool SCALE>
__device__ __forceinline__ void mlp_body(
    char* smem, int m0, int c0,
    const unsigned short* __restrict__ A, const unsigned short* __restrict__ WT,
    const unsigned short* __restrict__ bias, unsigned short* __restrict__ out,
    const float* __restrict__ dinv) {
  short* As = (short*)smem;             // 128*40
  short* Bs = (short*)(smem + 10240);   // 128*40
  const int t = threadIdx.x;
  const int lane = t & 63, wv = t >> 6;
  const int mw = (wv >> 1) * 64, nw = (wv & 1) * 64;
  const int lr = lane & 15, lq = lane >> 4;

  f32x4 acc[4][4];
#pragma unroll
  for (int i = 0; i < 4; ++i)
#pragma unroll
    for (int j = 0; j < 4; ++j) acc[i][j] = (f32x4)0.f;

  for (int kc = 0; kc < K; kc += 32) {
    __syncthreads();
#pragma unroll
    for (int it = 0; it < 2; ++it) {
      int idx = t + it * 256;
      int row = idx >> 2, seg = idx & 3;
      uint4 u = make_uint4(0, 0, 0, 0);
      int gr = m0 + row;
      if (gr < NNODES) u = *(const uint4*)(A + (size_t)gr * K + kc + seg * 8);
      *(uint4*)&As[row * 40 + seg * 8] = u;
      uint4 v = *(const uint4*)(WT + (size_t)(c0 + row) * K + kc + seg * 8);
      *(uint4*)&Bs[row * 40 + seg * 8] = v;
    }
    __syncthreads();
    bf16x8 af[4], bfr[4];
#pragma unroll
    for (int i = 0; i < 4; ++i)
      af[i] = *(const bf16x8*)&As[(mw + 16 * i + lr) * 40 + lq * 8];
#pragma unroll
    for (int j = 0; j < 4; ++j)
      bfr[j] = *(const bf16x8*)&Bs[(nw + 16 * j + lr) * 40 + lq * 8];
#pragma unroll
    for (int i = 0; i < 4; ++i)
#pragma unroll
      for (int j = 0; j < 4; ++j)
        acc[i][j] = __builtin_amdgcn_mfma_f32_16x16x32_bf16(af[i], bfr[j], acc[i][j], 0, 0, 0);
  }

  float bv[4];
#pragma unroll
  for (int j = 0; j < 4; ++j) bv[j] = bf2f((unsigned)bias[c0 + nw + 16 * j + lr]);
#pragma unroll
  for (int i = 0; i < 4; ++i) {
    int rbase = m0 + mw + 16 * i + lq * 4;
#pragma unroll
    for (int r = 0; r < 4; ++r) {
      int row = rbase + r;
      if (row < NNODES) {
        float s = SCALE ? dinv[row] : 1.f;
#pragma unroll
        for (int j = 0; j < 4; ++j) {
          int col = c0 + nw + 16 * j + lr;
          float v = fmaxf(acc[i][j][r] + bv[j], 0.f) * s;
          out[(size_t)row * 256 + col] = f2bf(v);
        }
      }
    }
  }
}

// exit: (A@We) 128-row tile; SOFTMAX -> f32 log-softmax rows, else P*dinv bf16
template <int K, bool SOFTMAX>
__device__ __forceinline__ void exit_body(
    char* smem, int m0,
    const unsigned short* __restrict__ A, const unsigned short* __restrict__ WT,
    const unsigned short* __restrict__ bias, float* __restrict__ outp,
    unsigned short* __restrict__ Pout, const float* __restrict__ dinv) {
  constexpr int KP = K + 8;
  short* As = (short*)smem;             // 128*40
  short* Bs = (short*)(smem + 10240);   // 48*KP
  const int t = threadIdx.x;
  const int lane = t & 63, wv = t >> 6;
  const int mw = wv * 32;
  const int lr = lane & 15, lq = lane >> 4;

  for (int idx = t; idx < 48 * (K / 8); idx += 256) {
    int row = idx / (K / 8), seg = idx % (K / 8);
    uint4 w = *(const uint4*)(WT + (size_t)row * K + seg * 8);
    *(uint4*)&Bs[row * KP + seg * 8] = w;
  }

  f32x4 acc[2][3];
#pragma unroll
  for (int i = 0; i < 2; ++i)
#pragma unroll
    for (int j = 0; j < 3; ++j) acc[i][j] = (f32x4)0.f;

  for (int kc = 0; kc < K; kc += 32) {
    __syncthreads();
#pragma unroll
    for (int it = 0; it < 2; ++it) {
      int idx = t + it * 256;
      int row = idx >> 2, seg = idx & 3;
      uint4 u = make_uint4(0, 0, 0, 0);
      int gr = m0 + row;
      if (gr < NNODES) u = *(const uint4*)(A + (size_t)gr * K + kc + seg * 8);
      *(uint4*)&As[row * 40 + seg * 8] = u;
    }
    __syncthreads();
    bf16x8 af[2], bfr[3];
#pragma unroll
    for (int i = 0; i < 2; ++i)
      af[i] = *(const bf16x8*)&As[(mw + 16 * i + lr) * 40 + lq * 8];
#pragma unroll
    for (int j = 0; j < 3; ++j)
      bfr[j] = *(const bf16x8*)&Bs[(16 * j + lr) * KP + kc + lq * 8];
#pragma unroll
    for (int i = 0; i < 2; ++i)
#pragma unroll
      for (int j = 0; j < 3; ++j)
        acc[i][j] = __builtin_amdgcn_mfma_f32_16x16x32_bf16(af[i], bfr[j], acc[i][j], 0, 0, 0);
  }

  if (SOFTMAX) {
    float bv0 = bf2f((unsigned)bias[lr]);
    float bv1 = bf2f((unsigned)bias[16 + lr]);
    float bv2 = (lr < 8) ? bf2f((unsigned)bias[32 + lr]) : 0.f;
#pragma unroll
    for (int i = 0; i < 2; ++i) {
#pragma unroll
      for (int r = 0; r < 4; ++r) {
        int row = m0 + mw + 16 * i + lq * 4 + r;
        float v0 = acc[i][0][r] + bv0;
        float v1 = acc[i][1][r] + bv1;
        float v2 = (lr < 8) ? (acc[i][2][r] + bv2) : -1e30f;
        float m = fmaxf(fmaxf(v0, v1), v2);
#pragma unroll
        for (int o = 8; o > 0; o >>= 1) m = fmaxf(m, __shfl_xor(m, o, 16));
        float ss = expf(v0 - m) + expf(v1 - m) + ((lr < 8) ? expf(v2 - m) : 0.f);
#pragma unroll
        for (int o = 8; o > 0; o >>= 1) ss += __shfl_xor(ss, o, 16);
        float ls = logf(ss) + m;
        if (row < NNODES) {
          outp[(size_t)row * 160 + lr] = v0 - ls;
          outp[(size_t)row * 160 + 16 + lr] = v1 - ls;
          if (lr < 8) outp[(size_t)row * 160 + 32 + lr] = v2 - ls;
        }
      }
    }
  } else {
#pragma unroll
    for (int i = 0; i < 2; ++i) {
#pragma unroll
      for (int r = 0; r < 4; ++r) {
        int row = m0 + mw + 16 * i + lq * 4 + r;
        if (row < NNODES) {
          float s = dinv[row];
          Pout[(size_t)row * 40 + lr] = f2bf(acc[i][0][r] * s);
          Pout[(size_t)row * 40 + 16 + lr] = f2bf(acc[i][1][r] * s);
          if (lr < 8) Pout[(size_t)row * 40 + 32 + lr] = f2bf(acc[i][2][r] * s);
        }
      }
    }
  }
}

// ---------- kernels wrapping the bodies ----------
template <int K> struct ExitSM { static constexpr int B = 10240 + 48 * (K + 8) * 2; };

__global__ __launch_bounds__(256) void k_exit0(
    const unsigned short* __restrict__ A, const unsigned short* __restrict__ WT,
    const unsigned short* __restrict__ bias, float* __restrict__ outp,
    const float* __restrict__ dinv) {
  __shared__ __align__(16) char smem[ExitSM<128>::B];
  exit_body<128, true>(smem, blockIdx.x * 128, A, WT, bias, outp, nullptr, dinv);
}

__global__ __launch_bounds__(256) void k_exit3(
    const unsigned short* __restrict__ A, const unsigned short* __restrict__ WT,
    unsigned short* __restrict__ Pout, const float* __restrict__ dinv) {
  __shared__ __align__(16) char smem[ExitSM<256>::B];
  exit_body<256, false>(smem, blockIdx.x * 128, A, WT, nullptr, nullptr, Pout, dinv);
}

// heterogeneous: blocks [0,1564) mlp (128x128 tiles, 2 col-halves);
// blocks [1564, 2346) exit+softmax. Both read the same A.
template <int K, bool MLPSCALE>
__global__ __launch_bounds__(256) void k_exit_mlp(
    const unsigned short* __restrict__ A,
    const unsigned short* __restrict__ WTmlp, const unsigned short* __restrict__ bmlp,
    unsigned short* __restrict__ outmlp,
    const unsigned short* __restrict__ WTex, const unsigned short* __restrict__ bex,
    float* __restrict__ outp, const float* __restrict__ dinv) {
  constexpr int SM = (ExitSM<K>::B > 20480) ? ExitSM<K>::B : 20480;
  __shared__ __align__(16) char smem[SM];
  int bid = blockIdx.x;
  if (bid < 1564) {
    mlp_body<K, MLPSCALE>(smem, (bid >> 1) * 128, (bid & 1) * 128, A, WTmlp, bmlp, outmlp, dinv);
  } else {
    exit_body<K, true>(smem, (bid - 1564) * 128, A, WTex, bex, outp, nullptr, dinv);
  }
}

// ---------- launch ----------
extern "C" void kernel_launch(void* const* d_in, const int* in_sizes, int n_in,
                              void* d_out, int out_size, void* d_ws, size_t ws_size,
                              hipStream_t stream) {
  const void* x_raw   = d_in[0];
  const int* ei       = (const int*)d_in[1];
  float* out          = (float*)d_out;

  char* ws = (char*)d_ws;
  int*   flags    = (int*)(ws + 0);
  int*   bcnt     = (int*)(ws + 4096);
  int*   gcur     = (int*)(ws + 8192);
  int*   bbase    = (int*)(ws + 12288);
  float* dinv     = (float*)(ws + 524288);
  int*   offs     = (int*)(ws + 1048576);
  int*   csr_src  = (int*)(ws + 2097152);   // 6.4 MB
  int*   stage    = (int*)(ws + 8650752);   // 6.4 MB
  unsigned short* xb = (unsigned short*)(ws + 16777216);   // N*128 bf16 (reused as P)
  unsigned short* wb = (unsigned short*)(ws + 45088768);   // weights
  unsigned short* hA = (unsigned short*)(ws + 48234496);   // N*256 bf16
  unsigned short* hB = (unsigned short*)(ws + 100663296);  // N*256 bf16
  unsigned short* xs = hB;  // prescaled x aliases hB (dead until mlp128 writes it)
  unsigned short* P  = xb;

  unsigned short* bc0 = wb + 32768;
  unsigned short* bc1 = wb + 98560;
  unsigned short* be0 = wb + 103936;
  unsigned short* be1 = wb + 109096;
  unsigned short* be2 = wb + 119376;
  unsigned short* be3 = wb + 129656;
  unsigned short* WTc0  = wb + 131072;  // 256 x 128
  unsigned short* WTc1  = wb + 163840;  // 256 x 256
  unsigned short* WT40e0 = wb + 229376; // 48 x 128
  unsigned short* WT40e1 = wb + 235520; // 48 x 128
  unsigned short* WT40e2 = wb + 241664; // 48 x 256
  unsigned short* WT40e3 = wb + 253952; // 48 x 256

  dim3 B(256);
  // bucketed CSR build (bcnt block 0 also probes x dtype -> flags[0])
  k_zero<<<dim3(4), B, 0, stream>>>(bcnt, NBKT);
  k_bcnt<<<dim3(391), B, 0, stream>>>(ei, bcnt, (const unsigned*)x_raw, flags);
  k_bscan2<<<dim3(1), dim3(64), 0, stream>>>(bcnt, bbase, gcur);
  k_bstage<<<dim3(391), B, 0, stream>>>(ei, gcur, stage);
  k_bplace<<<dim3(NBKT), B, 0, stream>>>(stage, bbase, offs, dinv, csr_src);

  // convert x (+xs prescale), biases, and raw-W transposes in one dispatch
  CvtP p;
  const int bsrc[7] = {0, 3, 5, 9, 11, 13, 15};
  unsigned short* bdst[7] = {xb, bc0, bc1, be0, be1, be2, be3};
  const int bn[7] = {NNODES * 128, 256, 256, 40, 40, 40, 40};
  for (int i = 0; i < 7; ++i) { p.src[i] = d_in[bsrc[i]]; p.dst[i] = bdst[i]; p.n[i] = bn[i]; }
  const int wsrc[6] = {2, 4, 8, 10, 12, 14};
  unsigned short* wdst[6] = {WTc0, WTc1, WT40e0, WT40e1, WT40e2, WT40e3};
  for (int i = 0; i < 6; ++i) { p.W[i] = d_in[wsrc[i]]; p.WT[i] = wdst[i]; }
  k_cvt<<<dim3(1024, 8), B, 0, stream>>>(p, flags, dinv, xs);

  // layer 0: exit on x
  k_exit0<<<dim3(782), B, 0, stream>>>(xb, WT40e0, be0, out + 0 * 40, dinv);
  // h1 = agg(xs)
  k_agg<128, 16><<<dim3(25000), B, 0, stream>>>(xs, hA, offs, csr_src, dinv);
  // exit1(hA) || hB = relu(hA Wc0 + bc0)*dinv
  k_exit_mlp<128, true><<<dim3(2346), B, 0, stream>>>(hA, WTc0, bc0, hB,
                                                      WT40e1, be1, out + 1 * 40, dinv);
  // h2 = agg(hB)
  k_agg<256, 8><<<dim3(25000), B, 0, stream>>>(hB, hA, offs, csr_src, dinv);
  // exit2(hA) || hB = relu(hA Wc1 + bc1)
  k_exit_mlp<256, false><<<dim3(2346), B, 0, stream>>>(hA, WTc1, bc1, hB,
                                                       WT40e2, be2, out + 2 * 40, dinv);
  // layer 3 push-through: P = (hB @ We3) * dinv
  k_exit3<<<dim3(782), B, 0, stream>>>(hB, WT40e3, P, dinv);
  k_agg40<<<dim3(25000), B, 0, stream>>>(P, offs, csr_src, dinv, be3, out + 3 * 40);
}